// Round 3
// baseline (737.014 us; speedup 1.0000x reference)
//
#include <hip/hip_runtime.h>
#include <math.h>

#define NB 8
#define CHN 256
#define HWD 96
#define PIXN (HWD*HWD)        // 9216 pixels per image
#define TOTPIX (NB*PIXN)      // 73728
#define VCN 512
#define OHW 30
#define LPP (OHW*OHW)         // 900 patches per image
#define NPATCH (NB*LPP)       // 7200
#define INPD 320
#define HID 768

__device__ __forceinline__ float f4c(const float4 v, int i){
  return i==0 ? v.x : i==1 ? v.y : i==2 ? v.z : v.w;
}

// ---------------- norms ----------------
__global__ void wnorm_k(const float* __restrict__ cw, float* __restrict__ invw){
  int v = blockIdx.x*256 + threadIdx.x;
  if (v >= VCN) return;
  const float* r = cw + (size_t)v*CHN;
  float s = 0.f;
  #pragma unroll 4
  for (int c=0;c<CHN;c++){ float t=r[c]; s = fmaf(t,t,s); }
  invw[v] = 1.0f/sqrtf(s);
}

__global__ void pixnorm_k(const float* __restrict__ x, float* __restrict__ invpix){
  int p = blockIdx.x*256 + threadIdx.x;
  if (p >= TOTPIX) return;
  int n = p / PIXN, pl = p % PIXN;
  const float* xp = x + (size_t)n*CHN*PIXN + pl;
  float s = 0.f;
  #pragma unroll 4
  for (int c=0;c<CHN;c++){ float t = xp[(size_t)c*PIXN]; s = fmaf(t,t,s); }
  invpix[p] = 1.0f/sqrtf(s);
}

// ---------------- per-pixel cosine-sim GEMM + per-tile argmax ----------------
// 128x128 block tile, 8x8/thread. All fragments are genuine float4 locals
// (no type-punned local arrays -> SROA keeps everything in arch VGPRs;
// round-2's punned float[8] arrays got spilled, VGPR_Count=60).
__global__ __launch_bounds__(256,2) void gemm_z_k(
    const float* __restrict__ x, const float* __restrict__ cw,
    const float* __restrict__ invpix, const float* __restrict__ invw,
    float* __restrict__ mcand, int* __restrict__ vcand){
  __shared__ __align__(16) char smem[17408];
  float (*As)[132] = (float(*)[132])smem;                 // [16][132] 8448 B
  float (*Bs)[132] = (float(*)[132])(smem + 8448);        // [16][132] 8448 B
  const int t = threadIdx.x;
  const int m0 = blockIdx.y * 128;
  const int v0 = blockIdx.x * 128;
  const int img = m0 / PIXN;
  const int pl0 = m0 % PIXN;
  const float* xb = x + (size_t)img*CHN*PIXN + pl0;
  const int tm = t & 15, tn = t >> 4;
  const int k_a = t >> 4, m_a = (t & 15) * 8;   // A staging
  const int v_b = t >> 1, k_b = (t & 1) * 8;    // B staging (transpose scatter)
  float4 acc[8][2];
  #pragma unroll
  for (int i=0;i<8;i++){ acc[i][0] = make_float4(0.f,0.f,0.f,0.f);
                         acc[i][1] = make_float4(0.f,0.f,0.f,0.f); }
  for (int k0 = 0; k0 < CHN; k0 += 16){
    const float4 a4l = *(const float4*)&xb[(size_t)(k0+k_a)*PIXN + m_a];
    const float4 a4h = *(const float4*)&xb[(size_t)(k0+k_a)*PIXN + m_a + 4];
    const float4 b4l = *(const float4*)&cw[(size_t)(v0+v_b)*CHN + k0 + k_b];
    const float4 b4h = *(const float4*)&cw[(size_t)(v0+v_b)*CHN + k0 + k_b + 4];
    __syncthreads();
    *(float4*)&As[k_a][m_a]     = a4l;
    *(float4*)&As[k_a][m_a + 4] = a4h;
    Bs[k_b+0][v_b]=b4l.x; Bs[k_b+1][v_b]=b4l.y; Bs[k_b+2][v_b]=b4l.z; Bs[k_b+3][v_b]=b4l.w;
    Bs[k_b+4][v_b]=b4h.x; Bs[k_b+5][v_b]=b4h.y; Bs[k_b+6][v_b]=b4h.z; Bs[k_b+7][v_b]=b4h.w;
    __syncthreads();
    #pragma unroll
    for (int k=0;k<16;k++){
      const float4 al = *(const float4*)&As[k][tm*4];
      const float4 ah = *(const float4*)&As[k][64 + tm*4];
      const float4 bl = *(const float4*)&Bs[k][tn*4];
      const float4 bh = *(const float4*)&Bs[k][64 + tn*4];
      #pragma unroll
      for (int i=0;i<8;i++){
        const float ai = f4c(i<4 ? al : ah, i & 3);
        acc[i][0].x = fmaf(ai, bl.x, acc[i][0].x);
        acc[i][0].y = fmaf(ai, bl.y, acc[i][0].y);
        acc[i][0].z = fmaf(ai, bl.z, acc[i][0].z);
        acc[i][0].w = fmaf(ai, bl.w, acc[i][0].w);
        acc[i][1].x = fmaf(ai, bh.x, acc[i][1].x);
        acc[i][1].y = fmaf(ai, bh.y, acc[i][1].y);
        acc[i][1].z = fmaf(ai, bh.z, acc[i][1].z);
        acc[i][1].w = fmaf(ai, bh.w, acc[i][1].w);
      }
    }
  }
  // epilogue: per-pixel argmax over this block's 128 v values
  float iwv[8];
  #pragma unroll
  for (int jb=0;jb<2;jb++)
    #pragma unroll
    for (int j=0;j<4;j++) iwv[jb*4+j] = invw[v0 + jb*64 + tn*4 + j];
  __syncthreads();                          // done reading As/Bs; reuse smem
  float (*rv)[17] = (float(*)[17])smem;     // [128][17]
  int   (*ri)[17] = (int(*)[17])(smem + 8704);
  #pragma unroll
  for (int i=0;i<8;i++){
    const int r = (i<4) ? tm*4 + i : 64 + tm*4 + (i-4);
    const float ip = invpix[m0 + r];
    float bz = -1e30f; int bvi = 0;
    #pragma unroll
    for (int jb=0;jb<2;jb++){
      #pragma unroll
      for (int j=0;j<4;j++){               // ascending v within tile
        const float z = f4c(acc[i][jb], j) * ip * iwv[jb*4+j];
        const int vv = v0 + jb*64 + tn*4 + j;
        if (z > bz){ bz = z; bvi = vv; }   // strict > keeps lowest v on tie
      }
    }
    rv[r][tn] = bz; ri[r][tn] = bvi;
  }
  __syncthreads();
  if (t < 128){
    float best = rv[t][0]; int bi = ri[t][0];
    #pragma unroll
    for (int s=1;s<16;s++){
      float v2 = rv[t][s]; int i2 = ri[t][s];
      if (v2 > best || (v2 == best && i2 < bi)){ best=v2; bi=i2; }
    }
    mcand[(size_t)(m0+t)*4 + blockIdx.x] = best;
    vcand[(size_t)(m0+t)*4 + blockIdx.x] = bi;
  }
}

// ---------------- per-patch selection, builds MLP input (7200 x 320) ----------------
__global__ void select_k(const float* __restrict__ x, const float* __restrict__ cw,
    const float* __restrict__ invpix, const float* __restrict__ invw,
    const float* __restrict__ mcand, const int* __restrict__ vcand,
    float* __restrict__ inp){
  const int q = blockIdx.x;      // patch id
  const int lane = threadIdx.x;  // 0..63 = window position ky*8+kx
  const int n = q / LPP, l = q % LPP;
  const int oy = l / OHW, ox = l % OHW;
  const int pl = (oy*3 + (lane >> 3))*HWD + (ox*3 + (lane & 7));
  const int p = n*PIXN + pl;
  float best = -1e30f; int bv = 0;
  #pragma unroll
  for (int s=0;s<4;s++){
    float v2 = mcand[(size_t)p*4 + s];
    int i2 = vcand[(size_t)p*4 + s];
    if (v2 > best || (v2 == best && i2 < bv)){ best = v2; bv = i2; }
  }
  float val = best;
  int flat = bv*64 + lane;
  #pragma unroll
  for (int off=32; off>0; off>>=1){
    float ov = __shfl_xor(val, off);
    int of = __shfl_xor(flat, off);
    if (ov > val || (ov == val && of < flat)){ val = ov; flat = of; }
  }
  const int mch = flat >> 6;
  const int pos = flat & 63;
  const float ms = val;
  const float* xp = x + (size_t)n*CHN*PIXN + pl;
  const float* wr = cw + (size_t)mch*CHN;
  float d0=0.f,d1=0.f,d2=0.f,d3=0.f;
  for (int c=0;c<CHN;c+=4){
    d0 = fmaf(xp[(size_t)(c+0)*PIXN], wr[c+0], d0);
    d1 = fmaf(xp[(size_t)(c+1)*PIXN], wr[c+1], d1);
    d2 = fmaf(xp[(size_t)(c+2)*PIXN], wr[c+2], d2);
    d3 = fmaf(xp[(size_t)(c+3)*PIXN], wr[c+3], d3);
  }
  float sim = ((d0+d1)+(d2+d3)) * invpix[p] * invw[mch];
  inp[(size_t)q*INPD + 256 + lane] = sim;
  const int wpl = (oy*3 + (pos>>3))*HWD + (ox*3 + (pos&7));
  const float* xw = x + (size_t)n*CHN*PIXN + wpl;
  const float om = 1.0f - ms;
  #pragma unroll
  for (int tt=0;tt<4;tt++){
    int c = lane + 64*tt;
    float act = xw[(size_t)c*PIXN];
    inp[(size_t)q*INPD + c] = fmaf(act, ms, wr[c]*om);
  }
}

// ---------------- MLP GEMMs: C = act(A @ B^T + bias) ----------------
// 128x128 tile, 8x8/thread, float4-only locals. N multiple of 128; M guarded.
template<int EPI>
__global__ __launch_bounds__(256,2) void gemm_rm_k(
    const float* __restrict__ A, const float* __restrict__ B,
    const float* __restrict__ bias, float* __restrict__ C,
    int M, int N, int K){
  __shared__ __align__(16) char smem[16896];
  float (*As)[132] = (float(*)[132])smem;
  float (*Bs)[132] = (float(*)[132])(smem + 8448);
  const int t = threadIdx.x;
  const int n0 = blockIdx.x * 128;
  const int m0 = blockIdx.y * 128;
  const int tm = t & 15, tn = t >> 4;
  const int r_s = t >> 1, k_s = (t & 1) * 8;
  float4 acc[8][2];
  #pragma unroll
  for (int i=0;i<8;i++){ acc[i][0] = make_float4(0.f,0.f,0.f,0.f);
                         acc[i][1] = make_float4(0.f,0.f,0.f,0.f); }
  for (int k0 = 0; k0 < K; k0 += 16){
    float4 a4l = make_float4(0.f,0.f,0.f,0.f), a4h = a4l;
    if (m0 + r_s < M){
      a4l = *(const float4*)&A[(size_t)(m0+r_s)*K + k0 + k_s];
      a4h = *(const float4*)&A[(size_t)(m0+r_s)*K + k0 + k_s + 4];
    }
    const float4 b4l = *(const float4*)&B[(size_t)(n0+r_s)*K + k0 + k_s];
    const float4 b4h = *(const float4*)&B[(size_t)(n0+r_s)*K + k0 + k_s + 4];
    __syncthreads();
    As[k_s+0][r_s]=a4l.x; As[k_s+1][r_s]=a4l.y; As[k_s+2][r_s]=a4l.z; As[k_s+3][r_s]=a4l.w;
    As[k_s+4][r_s]=a4h.x; As[k_s+5][r_s]=a4h.y; As[k_s+6][r_s]=a4h.z; As[k_s+7][r_s]=a4h.w;
    Bs[k_s+0][r_s]=b4l.x; Bs[k_s+1][r_s]=b4l.y; Bs[k_s+2][r_s]=b4l.z; Bs[k_s+3][r_s]=b4l.w;
    Bs[k_s+4][r_s]=b4h.x; Bs[k_s+5][r_s]=b4h.y; Bs[k_s+6][r_s]=b4h.z; Bs[k_s+7][r_s]=b4h.w;
    __syncthreads();
    #pragma unroll
    for (int k=0;k<16;k++){
      const float4 al = *(const float4*)&As[k][tm*4];
      const float4 ah = *(const float4*)&As[k][64 + tm*4];
      const float4 bl = *(const float4*)&Bs[k][tn*4];
      const float4 bh = *(const float4*)&Bs[k][64 + tn*4];
      #pragma unroll
      for (int i=0;i<8;i++){
        const float ai = f4c(i<4 ? al : ah, i & 3);
        acc[i][0].x = fmaf(ai, bl.x, acc[i][0].x);
        acc[i][0].y = fmaf(ai, bl.y, acc[i][0].y);
        acc[i][0].z = fmaf(ai, bl.z, acc[i][0].z);
        acc[i][0].w = fmaf(ai, bl.w, acc[i][0].w);
        acc[i][1].x = fmaf(ai, bh.x, acc[i][1].x);
        acc[i][1].y = fmaf(ai, bh.y, acc[i][1].y);
        acc[i][1].z = fmaf(ai, bh.z, acc[i][1].z);
        acc[i][1].w = fmaf(ai, bh.w, acc[i][1].w);
      }
    }
  }
  float bb[8];
  #pragma unroll
  for (int jb=0;jb<2;jb++)
    #pragma unroll
    for (int j=0;j<4;j++) bb[jb*4+j] = bias[n0 + jb*64 + tn*4 + j];
  #pragma unroll
  for (int i=0;i<8;i++){
    const int gm = m0 + ((i<4) ? tm*4 + i : 64 + tm*4 + (i-4));
    if (gm < M){
      #pragma unroll
      for (int jb=0;jb<2;jb++){
        float4 o;
        float v0 = f4c(acc[i][jb],0) + bb[jb*4+0];
        float v1 = f4c(acc[i][jb],1) + bb[jb*4+1];
        float v2 = f4c(acc[i][jb],2) + bb[jb*4+2];
        float v3 = f4c(acc[i][jb],3) + bb[jb*4+3];
        if (EPI == 1){
          o.x = v0 > 0.f ? v0 : 0.2f*v0; o.y = v1 > 0.f ? v1 : 0.2f*v1;
          o.z = v2 > 0.f ? v2 : 0.2f*v2; o.w = v3 > 0.f ? v3 : 0.2f*v3;
        } else {
          o.x = tanhf(v0); o.y = tanhf(v1); o.z = tanhf(v2); o.w = tanhf(v3);
        }
        *(float4*)&C[(size_t)gm*N + n0 + jb*64 + tn*4] = o;
      }
    }
  }
}

extern "C" void kernel_launch(void* const* d_in, const int* in_sizes, int n_in,
                              void* d_out, int out_size, void* d_ws, size_t ws_size,
                              hipStream_t stream){
  const float* x  = (const float*)d_in[0];
  const float* cw = (const float*)d_in[1];
  const float* W1 = (const float*)d_in[2];
  const float* b1 = (const float*)d_in[3];
  const float* W2 = (const float*)d_in[4];
  const float* b2 = (const float*)d_in[5];
  float* out = (float*)d_out;
  float* ws = (float*)d_ws;
  float* invpix = ws;                                  // 73728
  float* invw   = invpix + TOTPIX;                     // 512
  float* mcand  = invw + VCN;                          // 73728*4
  int*   vcand  = (int*)(mcand + (size_t)TOTPIX*4);    // 73728*4
  float* inp    = (float*)(vcand + (size_t)TOTPIX*4);  // 7200*320
  float* h1     = inp + (size_t)NPATCH*INPD;           // 7200*768

  wnorm_k<<<2,256,0,stream>>>(cw, invw);
  pixnorm_k<<<TOTPIX/256,256,0,stream>>>(x, invpix);
  gemm_z_k<<<dim3(VCN/128, TOTPIX/128),256,0,stream>>>(x, cw, invpix, invw, mcand, vcand);
  select_k<<<NPATCH,64,0,stream>>>(x, cw, invpix, invw, mcand, vcand, inp);
  gemm_rm_k<1><<<dim3(HID/128, (NPATCH+127)/128),256,0,stream>>>(inp, W1, b1, h1, NPATCH, HID, INPD);
  gemm_rm_k<2><<<dim3(CHN/128, (NPATCH+127)/128),256,0,stream>>>(h1, W2, b2, out, NPATCH, CHN, HID);
}

// Round 4
// 643.943 us; speedup vs baseline: 1.1445x; 1.1445x over previous
//
#include <hip/hip_runtime.h>
#include <math.h>

#define NB 8
#define CHN 256
#define HWD 96
#define PIXN (HWD*HWD)        // 9216 pixels per image
#define TOTPIX (NB*PIXN)      // 73728
#define VCN 512
#define OHW 30
#define LPP (OHW*OHW)         // 900
#define NPATCH (NB*LPP)       // 7200
#define INPD 320
#define HID 768

typedef unsigned short u16;
typedef __attribute__((ext_vector_type(8))) short bf16x8;
typedef __attribute__((ext_vector_type(8))) unsigned short us8;
typedef __attribute__((ext_vector_type(4))) float f32x4;

__device__ __forceinline__ float f4c(const float4 v, int i){
  return i==0 ? v.x : i==1 ? v.y : i==2 ? v.z : v.w;
}
// bf16 round-to-nearest-even via bit trick
__device__ __forceinline__ u16 bfrn(float f){
  unsigned u = __float_as_uint(f);
  return (u16)((u + 0x7fffu + ((u>>16)&1u)) >> 16);
}
__device__ __forceinline__ float bf2f(u16 h){
  return __uint_as_float(((unsigned)h)<<16);
}

// ---------------- norms ----------------
__global__ void wnorm_k(const float* __restrict__ cw, float* __restrict__ invw){
  int v = blockIdx.x*256 + threadIdx.x;
  if (v >= VCN) return;
  const float* r = cw + (size_t)v*CHN;
  float s = 0.f;
  #pragma unroll 4
  for (int c=0;c<CHN;c++){ float t=r[c]; s = fmaf(t,t,s); }
  invw[v] = 1.0f/sqrtf(s);
}

__global__ void pixnorm_k(const float* __restrict__ x, float* __restrict__ invpix){
  int p = blockIdx.x*256 + threadIdx.x;
  if (p >= TOTPIX) return;
  int n = p / PIXN, pl = p % PIXN;
  const float* xp = x + (size_t)n*CHN*PIXN + pl;
  float s = 0.f;
  #pragma unroll 4
  for (int c=0;c<CHN;c++){ float t = xp[(size_t)c*PIXN]; s = fmaf(t,t,s); }
  invpix[p] = 1.0f/sqrtf(s);
}

// ---------------- w 3-way bf16 split ----------------
__global__ void splitw_k(const float* __restrict__ cw, u16* __restrict__ w1,
                         u16* __restrict__ w2, u16* __restrict__ w3){
  int i = blockIdx.x*256 + threadIdx.x;   // VCN*CHN = 131072
  float a = cw[i];
  u16 h1 = bfrn(a);  float r1 = a - bf2f(h1);
  u16 h2 = bfrn(r1); float r2 = r1 - bf2f(h2);
  u16 h3 = bfrn(r2);
  w1[i]=h1; w2[i]=h2; w3[i]=h3;
}

// ---------------- x transpose: [img][c][pix] -> [img][pix][c] fp32 ----------------
__global__ __launch_bounds__(256) void xpose_k(const float* __restrict__ x,
                                               float* __restrict__ xt){
  __shared__ float ts[64][65];
  const int p0 = blockIdx.x*64, c0 = blockIdx.y*64, img = blockIdx.z;
  const int t = threadIdx.x, lp = t&63, sub = t>>6;
  const float* xb = x + (size_t)img*CHN*PIXN;
  #pragma unroll
  for (int r=0;r<16;r++){
    int cl = r*4 + sub;
    ts[cl][lp] = xb[(size_t)(c0+cl)*PIXN + p0 + lp];
  }
  __syncthreads();
  float* xo = xt + (size_t)img*PIXN*CHN;
  #pragma unroll
  for (int r=0;r<16;r++){
    int pl = r*4 + sub;
    xo[(size_t)(p0+pl)*CHN + c0 + lp] = ts[lp][pl];
  }
}

// ---------------- z GEMM via bf16x3-split MFMA + per-tile argmax ----------------
// Block tile 128 pix x 128 v, K-step 32. 4 waves each own a 64x64 quadrant as
// 4x4 grid of 16x16x32 MFMAs. 6 products: a1b1,a1b2,a2b1,a1b3,a2b2,a3b1
// -> z rel err ~2^-25 (argmax-flip prob ~1% over all 7200 patches).
// A-frag: A[m=lane&15][k=(lane>>4)*8+j]; C/D: row=(lane>>4)*4+reg, col=lane&15.
#define APAD 40                 // k-dim pad: 32->40 (80 B rows, 16B-aligned, conflict-light)
#define PL (128*APAD)           // LDS plane stride (ushorts)
__global__ __launch_bounds__(256,2) void gemm_z_k(
    const float* __restrict__ xt, const u16* __restrict__ w1,
    const u16* __restrict__ w2, const u16* __restrict__ w3,
    const float* __restrict__ invpix, const float* __restrict__ invw,
    float* __restrict__ mcand, int* __restrict__ vcand){
  __shared__ __align__(16) u16 sm[6*PL];   // As1,As2,As3,Bs1,Bs2,Bs3 = 61440 u16
  const int t = threadIdx.x;
  const int v0 = blockIdx.x * 128;
  const int m0 = blockIdx.y * 128;       // global pixel base (never crosses image: 9216%128==0)
  const int row = t>>1, half = (t&1)*16;
  const float* arow = xt + (size_t)(m0 + row)*CHN;
  const u16* b1r = w1 + (size_t)(v0+row)*CHN;
  const u16* b2r = w2 + (size_t)(v0+row)*CHN;
  const u16* b3r = w3 + (size_t)(v0+row)*CHN;
  const int lane = t & 63, wv = t >> 6;
  const int mq = wv & 1, nq = wv >> 1;
  const int col = lane & 15, qr = lane >> 4;
  f32x4 acc[4][4];
  #pragma unroll
  for (int i=0;i<4;i++)
    #pragma unroll
    for (int j=0;j<4;j++) acc[i][j] = (f32x4){0.f,0.f,0.f,0.f};

  for (int k0 = 0; k0 < CHN; k0 += 32){
    float4 ga0 = *(const float4*)&arow[k0+half+0];
    float4 ga1 = *(const float4*)&arow[k0+half+4];
    float4 ga2 = *(const float4*)&arow[k0+half+8];
    float4 ga3 = *(const float4*)&arow[k0+half+12];
    const uint4 gb1a = *(const uint4*)&b1r[k0+half], gb1b = *(const uint4*)&b1r[k0+half+8];
    const uint4 gb2a = *(const uint4*)&b2r[k0+half], gb2b = *(const uint4*)&b2r[k0+half+8];
    const uint4 gb3a = *(const uint4*)&b3r[k0+half], gb3b = *(const uint4*)&b3r[k0+half+8];
    __syncthreads();   // previous iteration's frag reads complete
    // A: split fp32 -> 3x bf16, write 2x us8 per split
    #pragma unroll
    for (int g=0; g<2; g++){
      us8 h1v, h2v, h3v;
      #pragma unroll
      for (int e=0; e<8; e++){
        const float a = f4c((g*2+(e>>2))==0?ga0:(g*2+(e>>2))==1?ga1:(g*2+(e>>2))==2?ga2:ga3, e&3);
        u16 x1 = bfrn(a);  float rr1 = a - bf2f(x1);
        u16 x2 = bfrn(rr1); float rr2 = rr1 - bf2f(x2);
        u16 x3 = bfrn(rr2);
        h1v[e]=x1; h2v[e]=x2; h3v[e]=x3;
      }
      *(us8*)&sm[0*PL + row*APAD + half + g*8] = h1v;
      *(us8*)&sm[1*PL + row*APAD + half + g*8] = h2v;
      *(us8*)&sm[2*PL + row*APAD + half + g*8] = h3v;
    }
    *(uint4*)&sm[3*PL + row*APAD + half]     = gb1a;
    *(uint4*)&sm[3*PL + row*APAD + half + 8] = gb1b;
    *(uint4*)&sm[4*PL + row*APAD + half]     = gb2a;
    *(uint4*)&sm[4*PL + row*APAD + half + 8] = gb2b;
    *(uint4*)&sm[5*PL + row*APAD + half]     = gb3a;
    *(uint4*)&sm[5*PL + row*APAD + half + 8] = gb3b;
    __syncthreads();
    bf16x8 bf0[4], bf1[4], bf2[4];
    #pragma unroll
    for (int ni=0; ni<4; ni++){
      const int bofs = (nq*64 + ni*16 + col)*APAD + qr*8;
      bf0[ni] = *(const bf16x8*)&sm[3*PL + bofs];
      bf1[ni] = *(const bf16x8*)&sm[4*PL + bofs];
      bf2[ni] = *(const bf16x8*)&sm[5*PL + bofs];
    }
    #pragma unroll
    for (int mi=0; mi<4; mi++){
      const int aofs = (mq*64 + mi*16 + col)*APAD + qr*8;
      const bf16x8 a1 = *(const bf16x8*)&sm[0*PL + aofs];
      const bf16x8 a2 = *(const bf16x8*)&sm[1*PL + aofs];
      const bf16x8 a3 = *(const bf16x8*)&sm[2*PL + aofs];
      #pragma unroll
      for (int ni=0; ni<4; ni++){
        f32x4 c = acc[mi][ni];
        c = __builtin_amdgcn_mfma_f32_16x16x32_bf16(a1, bf0[ni], c, 0,0,0);
        c = __builtin_amdgcn_mfma_f32_16x16x32_bf16(a1, bf1[ni], c, 0,0,0);
        c = __builtin_amdgcn_mfma_f32_16x16x32_bf16(a2, bf0[ni], c, 0,0,0);
        c = __builtin_amdgcn_mfma_f32_16x16x32_bf16(a1, bf2[ni], c, 0,0,0);
        c = __builtin_amdgcn_mfma_f32_16x16x32_bf16(a2, bf1[ni], c, 0,0,0);
        c = __builtin_amdgcn_mfma_f32_16x16x32_bf16(a3, bf0[ni], c, 0,0,0);
        acc[mi][ni] = c;
      }
    }
  }
  // ---- epilogue: per-pixel argmax over this block's 128 v ----
  float iw[4];
  #pragma unroll
  for (int ni=0; ni<4; ni++) iw[ni] = invw[v0 + nq*64 + ni*16 + col];
  __syncthreads();                       // done with frag LDS; reuse
  float* rlds = (float*)sm;              // [128][2] value
  int*   ilds = (int*)(sm + 2*PL);       // [128][2] index (offset 10240 B)
  #pragma unroll
  for (int mi=0; mi<4; mi++){
    #pragma unroll
    for (int r=0; r<4; r++){
      const int P = mq*64 + mi*16 + qr*4 + r;
      const float ip = invpix[m0 + P];
      float bz = -1e30f; int bvi = 0;
      #pragma unroll
      for (int ni=0; ni<4; ni++){        // ni ascending => v ascending
        const float z = f4c(*(const float4*)&acc[mi][ni], r) * ip * iw[ni];
        const int vv = v0 + nq*64 + ni*16 + col;
        if (z > bz){ bz = z; bvi = vv; }
      }
      #pragma unroll
      for (int off=1; off<16; off<<=1){  // reduce across col (16 lanes, same qr)
        const float oz = __shfl_xor(bz, off);
        const int  oi = __shfl_xor(bvi, off);
        if (oz > bz || (oz == bz && oi < bvi)){ bz = oz; bvi = oi; }
      }
      if (col == 0){ rlds[P*2+nq] = bz; ilds[P*2+nq] = bvi; }
    }
  }
  __syncthreads();
  if (t < 128){
    float z0 = rlds[t*2+0], z1 = rlds[t*2+1];
    int   i0 = ilds[t*2+0], i1 = ilds[t*2+1];
    float best = z0; int bi = i0;
    if (z1 > best || (z1 == best && i1 < bi)){ best = z1; bi = i1; }
    mcand[(size_t)(m0+t)*4 + blockIdx.x] = best;
    vcand[(size_t)(m0+t)*4 + blockIdx.x] = bi;
  }
}

// ---------------- per-patch selection, builds MLP input (7200 x 320) ----------------
__global__ void select_k(const float* __restrict__ x, const float* __restrict__ cw,
    const float* __restrict__ invpix, const float* __restrict__ invw,
    const float* __restrict__ mcand, const int* __restrict__ vcand,
    float* __restrict__ inp){
  const int q = blockIdx.x;
  const int lane = threadIdx.x;  // 0..63 = window position
  const int n = q / LPP, l = q % LPP;
  const int oy = l / OHW, ox = l % OHW;
  const int pl = (oy*3 + (lane >> 3))*HWD + (ox*3 + (lane & 7));
  const int p = n*PIXN + pl;
  float best = -1e30f; int bv = 0;
  #pragma unroll
  for (int s=0;s<4;s++){
    float v2 = mcand[(size_t)p*4 + s];
    int i2 = vcand[(size_t)p*4 + s];
    if (v2 > best || (v2 == best && i2 < bv)){ best = v2; bv = i2; }
  }
  float val = best;
  int flat = bv*64 + lane;
  #pragma unroll
  for (int off=32; off>0; off>>=1){
    float ov = __shfl_xor(val, off);
    int of = __shfl_xor(flat, off);
    if (ov > val || (ov == val && of < flat)){ val = ov; flat = of; }
  }
  const int mch = flat >> 6;
  const int pos = flat & 63;
  const float ms = val;
  const float* xp = x + (size_t)n*CHN*PIXN + pl;
  const float* wr = cw + (size_t)mch*CHN;
  float d0=0.f,d1=0.f,d2=0.f,d3=0.f;
  for (int c=0;c<CHN;c+=4){
    d0 = fmaf(xp[(size_t)(c+0)*PIXN], wr[c+0], d0);
    d1 = fmaf(xp[(size_t)(c+1)*PIXN], wr[c+1], d1);
    d2 = fmaf(xp[(size_t)(c+2)*PIXN], wr[c+2], d2);
    d3 = fmaf(xp[(size_t)(c+3)*PIXN], wr[c+3], d3);
  }
  float sim = ((d0+d1)+(d2+d3)) * invpix[p] * invw[mch];
  inp[(size_t)q*INPD + 256 + lane] = sim;
  const int wpl = (oy*3 + (pos>>3))*HWD + (ox*3 + (pos&7));
  const float* xw = x + (size_t)n*CHN*PIXN + wpl;
  const float om = 1.0f - ms;
  #pragma unroll
  for (int tt=0;tt<4;tt++){
    int c = lane + 64*tt;
    float act = xw[(size_t)c*PIXN];
    inp[(size_t)q*INPD + c] = fmaf(act, ms, wr[c]*om);
  }
}

// ---------------- MLP GEMMs: C = act(A @ B^T + bias) ----------------
template<int EPI>
__global__ __launch_bounds__(256,2) void gemm_rm_k(
    const float* __restrict__ A, const float* __restrict__ B,
    const float* __restrict__ bias, float* __restrict__ C,
    int M, int N, int K){
  __shared__ __align__(16) char smem[16896];
  float (*As)[132] = (float(*)[132])smem;
  float (*Bs)[132] = (float(*)[132])(smem + 8448);
  const int t = threadIdx.x;
  const int n0 = blockIdx.x * 128;
  const int m0 = blockIdx.y * 128;
  const int tm = t & 15, tn = t >> 4;
  const int r_s = t >> 1, k_s = (t & 1) * 8;
  float4 acc[8][2];
  #pragma unroll
  for (int i=0;i<8;i++){ acc[i][0] = make_float4(0.f,0.f,0.f,0.f);
                         acc[i][1] = make_float4(0.f,0.f,0.f,0.f); }
  for (int k0 = 0; k0 < K; k0 += 16){
    float4 a4l = make_float4(0.f,0.f,0.f,0.f), a4h = a4l;
    if (m0 + r_s < M){
      a4l = *(const float4*)&A[(size_t)(m0+r_s)*K + k0 + k_s];
      a4h = *(const float4*)&A[(size_t)(m0+r_s)*K + k0 + k_s + 4];
    }
    const float4 b4l = *(const float4*)&B[(size_t)(n0+r_s)*K + k0 + k_s];
    const float4 b4h = *(const float4*)&B[(size_t)(n0+r_s)*K + k0 + k_s + 4];
    __syncthreads();
    As[k_s+0][r_s]=a4l.x; As[k_s+1][r_s]=a4l.y; As[k_s+2][r_s]=a4l.z; As[k_s+3][r_s]=a4l.w;
    As[k_s+4][r_s]=a4h.x; As[k_s+5][r_s]=a4h.y; As[k_s+6][r_s]=a4h.z; As[k_s+7][r_s]=a4h.w;
    Bs[k_s+0][r_s]=b4l.x; Bs[k_s+1][r_s]=b4l.y; Bs[k_s+2][r_s]=b4l.z; Bs[k_s+3][r_s]=b4l.w;
    Bs[k_s+4][r_s]=b4h.x; Bs[k_s+5][r_s]=b4h.y; Bs[k_s+6][r_s]=b4h.z; Bs[k_s+7][r_s]=b4h.w;
    __syncthreads();
    #pragma unroll
    for (int k=0;k<16;k++){
      const float4 al = *(const float4*)&As[k][tm*4];
      const float4 ah = *(const float4*)&As[k][64 + tm*4];
      const float4 bl = *(const float4*)&Bs[k][tn*4];
      const float4 bh = *(const float4*)&Bs[k][64 + tn*4];
      #pragma unroll
      for (int i=0;i<8;i++){
        const float ai = f4c(i<4 ? al : ah, i & 3);
        acc[i][0].x = fmaf(ai, bl.x, acc[i][0].x);
        acc[i][0].y = fmaf(ai, bl.y, acc[i][0].y);
        acc[i][0].z = fmaf(ai, bl.z, acc[i][0].z);
        acc[i][0].w = fmaf(ai, bl.w, acc[i][0].w);
        acc[i][1].x = fmaf(ai, bh.x, acc[i][1].x);
        acc[i][1].y = fmaf(ai, bh.y, acc[i][1].y);
        acc[i][1].z = fmaf(ai, bh.z, acc[i][1].z);
        acc[i][1].w = fmaf(ai, bh.w, acc[i][1].w);
      }
    }
  }
  float bb[8];
  #pragma unroll
  for (int jb=0;jb<2;jb++)
    #pragma unroll
    for (int j=0;j<4;j++) bb[jb*4+j] = bias[n0 + jb*64 + tn*4 + j];
  #pragma unroll
  for (int i=0;i<8;i++){
    const int gm = m0 + ((i<4) ? tm*4 + i : 64 + tm*4 + (i-4));
    if (gm < M){
      #pragma unroll
      for (int jb=0;jb<2;jb++){
        float4 o;
        float v0 = f4c(acc[i][jb],0) + bb[jb*4+0];
        float v1 = f4c(acc[i][jb],1) + bb[jb*4+1];
        float v2 = f4c(acc[i][jb],2) + bb[jb*4+2];
        float v3 = f4c(acc[i][jb],3) + bb[jb*4+3];
        if (EPI == 1){
          o.x = v0 > 0.f ? v0 : 0.2f*v0; o.y = v1 > 0.f ? v1 : 0.2f*v1;
          o.z = v2 > 0.f ? v2 : 0.2f*v2; o.w = v3 > 0.f ? v3 : 0.2f*v3;
        } else {
          o.x = tanhf(v0); o.y = tanhf(v1); o.z = tanhf(v2); o.w = tanhf(v3);
        }
        *(float4*)&C[(size_t)gm*N + n0 + jb*64 + tn*4] = o;
      }
    }
  }
}

extern "C" void kernel_launch(void* const* d_in, const int* in_sizes, int n_in,
                              void* d_out, int out_size, void* d_ws, size_t ws_size,
                              hipStream_t stream){
  const float* x  = (const float*)d_in[0];
  const float* cw = (const float*)d_in[1];
  const float* W1 = (const float*)d_in[2];
  const float* b1 = (const float*)d_in[3];
  const float* W2 = (const float*)d_in[4];
  const float* b2 = (const float*)d_in[5];
  float* out = (float*)d_out;
  float* ws = (float*)d_ws;
  float* invpix = ws;                                        // 73728
  float* invw   = invpix + TOTPIX;                           // 512
  float* mcand  = invw + VCN;                                // TOTPIX*4
  int*   vcand  = (int*)(mcand + (size_t)TOTPIX*4);          // TOTPIX*4
  float* inp    = (float*)(vcand + (size_t)TOTPIX*4);        // 7200*320
  float* h1     = inp + (size_t)NPATCH*INPD;                 // 7200*768
  float* xt     = h1 + (size_t)NPATCH*HID;                   // TOTPIX*CHN fp32 (75.5 MB)
  u16*   w1s    = (u16*)(xt + (size_t)TOTPIX*CHN);           // VCN*CHN u16 x3
  u16*   w2s    = w1s + (size_t)VCN*CHN;
  u16*   w3s    = w2s + (size_t)VCN*CHN;
  // total ws use ~110 MB

  splitw_k<<<VCN*CHN/256,256,0,stream>>>(cw, w1s, w2s, w3s);
  wnorm_k<<<2,256,0,stream>>>(cw, invw);
  pixnorm_k<<<TOTPIX/256,256,0,stream>>>(x, invpix);
  xpose_k<<<dim3(PIXN/64, CHN/64, NB),256,0,stream>>>(x, xt);
  gemm_z_k<<<dim3(VCN/128, TOTPIX/128),256,0,stream>>>(xt, w1s, w2s, w3s, invpix, invw, mcand, vcand);
  select_k<<<NPATCH,64,0,stream>>>(x, cw, invpix, invw, mcand, vcand, inp);
  gemm_rm_k<1><<<dim3(HID/128, (NPATCH+127)/128),256,0,stream>>>(inp, W1, b1, h1, NPATCH, HID, INPD);
  gemm_rm_k<2><<<dim3(CHN/128, (NPATCH+127)/128),256,0,stream>>>(h1, W2, b2, out, NPATCH, CHN, HID);
}

// Round 5
// 560.034 us; speedup vs baseline: 1.3160x; 1.1498x over previous
//
#include <hip/hip_runtime.h>
#include <math.h>

#define NB 8
#define CHN 256
#define HWD 96
#define PIXN (HWD*HWD)        // 9216 pixels per image
#define TOTPIX (NB*PIXN)      // 73728
#define VCN 512
#define OHW 30
#define LPP (OHW*OHW)         // 900
#define NPATCH (NB*LPP)       // 7200
#define INPD 320
#define HID 768

typedef unsigned short u16;
typedef __attribute__((ext_vector_type(8))) short bf16x8;
typedef __attribute__((ext_vector_type(8))) unsigned short us8;
typedef __attribute__((ext_vector_type(4))) float f32x4;

__device__ __forceinline__ float f4c(const float4 v, int i){
  return i==0 ? v.x : i==1 ? v.y : i==2 ? v.z : v.w;
}
__device__ __forceinline__ u16 bfrn(float f){
  unsigned u = __float_as_uint(f);
  return (u16)((u + 0x7fffu + ((u>>16)&1u)) >> 16);
}
__device__ __forceinline__ float bf2f(u16 h){
  return __uint_as_float(((unsigned)h)<<16);
}

// Fragment-order layouts (chunk = 512 u16 = one wave frag-load of 1 KB):
//   xf[pt][kk][s][lane*8]  pt = global_pixel/16 (36864), kk = k/32 (8), s = split (3)
//   wf[vt][kk][s][lane*8]  vt = v/16 (32)
// lane = qr*16 + col; chunk holds elem[m or n = col][k = kk*32 + qr*8 + j].
// This IS the 16x16x32 MFMA A/B fragment layout -> one coalesced b128/lane.

// ---------------- norms ----------------
__global__ void wnorm_k(const float* __restrict__ cw, float* __restrict__ invw){
  int v = blockIdx.x*256 + threadIdx.x;
  if (v >= VCN) return;
  const float* r = cw + (size_t)v*CHN;
  float s = 0.f;
  #pragma unroll 4
  for (int c=0;c<CHN;c++){ float t=r[c]; s = fmaf(t,t,s); }
  invw[v] = 1.0f/sqrtf(s);
}

__global__ void pixnorm_k(const float* __restrict__ x, float* __restrict__ invpix){
  int p = blockIdx.x*256 + threadIdx.x;
  if (p >= TOTPIX) return;
  int n = p / PIXN, pl = p % PIXN;
  const float* xp = x + (size_t)n*CHN*PIXN + pl;
  float s = 0.f;
  #pragma unroll 4
  for (int c=0;c<CHN;c++){ float t = xp[(size_t)c*PIXN]; s = fmaf(t,t,s); }
  invpix[p] = 1.0f/sqrtf(s);
}

// ---------------- w -> 3-split bf16, fragment order ----------------
__global__ __launch_bounds__(64) void splitw_k(const float* __restrict__ cw,
                                               u16* __restrict__ wf){
  const int bx = blockIdx.x;             // vt*8 + kk  (256 blocks)
  const int vt = bx >> 3, kk = bx & 7;
  const int lane = threadIdx.x;
  const int qr = lane >> 4, vcol = lane & 15;
  const float* src = cw + (size_t)(vt*16 + vcol)*CHN + kk*32 + qr*8;
  us8 h1, h2, h3;
  #pragma unroll
  for (int j=0;j<8;j++){
    float a = src[j];
    u16 x1 = bfrn(a);  float r1 = a - bf2f(x1);
    u16 x2 = bfrn(r1); float r2 = r1 - bf2f(x2);
    h1[j]=x1; h2[j]=x2; h3[j]=bfrn(r2);
  }
  size_t base = (size_t)bx*3*512 + lane*8;
  *(us8*)&wf[base]      = h1;
  *(us8*)&wf[base+512]  = h2;
  *(us8*)&wf[base+1024] = h3;
}

// ---------------- x -> 3-split bf16, fragment order ----------------
__global__ __launch_bounds__(256) void xsplit_k(const float* __restrict__ x,
                                                u16* __restrict__ xf){
  __shared__ float ts[64][65];
  const int p0 = blockIdx.x*64, c0 = blockIdx.y*64, img = blockIdx.z;
  const int t = threadIdx.x, lp = t&63, sub = t>>6;
  const float* xb = x + (size_t)img*CHN*PIXN;
  #pragma unroll
  for (int r=0;r<16;r++){
    int cl = r*4 + sub;
    ts[cl][lp] = xb[(size_t)(c0+cl)*PIXN + p0 + lp];
  }
  __syncthreads();
  const int w = t>>6, lane = t&63;
  const int qr = lane>>4, pcol = lane&15;
  const size_t ptg = (size_t)(img*PIXN + p0)/16 + w;
  #pragma unroll
  for (int kkl=0;kkl<2;kkl++){
    const int kkg = (c0>>5) + kkl;
    us8 h1,h2,h3;
    #pragma unroll
    for (int j=0;j<8;j++){
      float a = ts[kkl*32 + qr*8 + j][w*16 + pcol];
      u16 x1 = bfrn(a);  float r1 = a - bf2f(x1);
      u16 x2 = bfrn(r1); float r2 = r1 - bf2f(x2);
      h1[j]=x1; h2[j]=x2; h3[j]=bfrn(r2);
    }
    size_t base = ((ptg*8 + kkg)*3)*512 + lane*8;
    *(us8*)&xf[base]      = h1;
    *(us8*)&xf[base+512]  = h2;
    *(us8*)&xf[base+1024] = h3;
  }
}

// ---------------- z GEMM: barrier-free, frags direct from global ----------------
// 128x128 block, 4 waves x (64x64 quadrant as 4x4 of 16x16x32 MFMA).
// 6 split-products. No staging LDS, no K-loop barriers.
__global__ __launch_bounds__(256,2) void gemm_z_k(
    const u16* __restrict__ xf, const u16* __restrict__ wf,
    const float* __restrict__ invpix, const float* __restrict__ invw,
    float* __restrict__ mcand, int* __restrict__ vcand){
  __shared__ float rv[128][2];
  __shared__ int   ri[128][2];
  const int t = threadIdx.x;
  const int v0 = blockIdx.x*128, m0 = blockIdx.y*128;
  const int lane = t&63, wv = t>>6;
  const int mq = wv&1, nq = wv>>1;
  const int col = lane&15, qr = lane>>4;
  const size_t loff = (size_t)lane*8;
  const int ptA0 = (m0>>4) + mq*4;
  const int vtB0 = (v0>>4) + nq*4;
  f32x4 acc[4][4];
  #pragma unroll
  for (int i=0;i<4;i++)
    #pragma unroll
    for (int j=0;j<4;j++) acc[i][j] = (f32x4){0.f,0.f,0.f,0.f};

  for (int kk=0; kk<8; kk++){
    bf16x8 a[4][3];
    #pragma unroll
    for (int mi=0;mi<4;mi++){
      const size_t ab = (((size_t)(ptA0+mi)*8 + kk)*3)*512 + loff;
      a[mi][0] = *(const bf16x8*)&xf[ab];
      a[mi][1] = *(const bf16x8*)&xf[ab+512];
      a[mi][2] = *(const bf16x8*)&xf[ab+1024];
    }
    #pragma unroll
    for (int ni=0;ni<4;ni++){
      const size_t bb = (((size_t)(vtB0+ni)*8 + kk)*3)*512 + loff;
      const bf16x8 b1 = *(const bf16x8*)&wf[bb];
      const bf16x8 b2 = *(const bf16x8*)&wf[bb+512];
      const bf16x8 b3 = *(const bf16x8*)&wf[bb+1024];
      #pragma unroll
      for (int mi=0;mi<4;mi++){
        f32x4 c = acc[mi][ni];
        c = __builtin_amdgcn_mfma_f32_16x16x32_bf16(a[mi][0], b1, c, 0,0,0);
        c = __builtin_amdgcn_mfma_f32_16x16x32_bf16(a[mi][0], b2, c, 0,0,0);
        c = __builtin_amdgcn_mfma_f32_16x16x32_bf16(a[mi][1], b1, c, 0,0,0);
        c = __builtin_amdgcn_mfma_f32_16x16x32_bf16(a[mi][0], b3, c, 0,0,0);
        c = __builtin_amdgcn_mfma_f32_16x16x32_bf16(a[mi][1], b2, c, 0,0,0);
        c = __builtin_amdgcn_mfma_f32_16x16x32_bf16(a[mi][2], b1, c, 0,0,0);
        acc[mi][ni] = c;
      }
    }
  }
  // ---- epilogue: per-pixel argmax over this block's 128 v ----
  float iw[4];
  #pragma unroll
  for (int ni=0; ni<4; ni++) iw[ni] = invw[v0 + nq*64 + ni*16 + col];
  #pragma unroll
  for (int mi=0; mi<4; mi++){
    #pragma unroll
    for (int r=0; r<4; r++){
      const int P = mq*64 + mi*16 + qr*4 + r;
      const float ip = invpix[m0 + P];
      float bz = -1e30f; int bvi = 0;
      #pragma unroll
      for (int ni=0; ni<4; ni++){        // ni ascending => v ascending
        const float z = f4c(*(const float4*)&acc[mi][ni], r) * ip * iw[ni];
        const int vv = v0 + nq*64 + ni*16 + col;
        if (z > bz){ bz = z; bvi = vv; }
      }
      #pragma unroll
      for (int off=1; off<16; off<<=1){  // reduce across 16 col lanes
        const float oz = __shfl_xor(bz, off);
        const int  oi = __shfl_xor(bvi, off);
        if (oz > bz || (oz == bz && oi < bvi)){ bz = oz; bvi = oi; }
      }
      if (col == 0){ rv[P][nq] = bz; ri[P][nq] = bvi; }
    }
  }
  __syncthreads();
  if (t < 128){
    float z0 = rv[t][0], z1 = rv[t][1];
    int   i0 = ri[t][0], i1 = ri[t][1];
    float best = z0; int bi = i0;
    if (z1 > best || (z1 == best && i1 < bi)){ best = z1; bi = i1; }
    mcand[(size_t)(m0+t)*4 + blockIdx.x] = best;
    vcand[(size_t)(m0+t)*4 + blockIdx.x] = bi;
  }
}

// ---------------- per-patch selection, builds MLP input (7200 x 320) ----------------
// Reads from xf frag planes (coalesced 16B chunks) instead of scattered x.
__global__ __launch_bounds__(64) void select_k(
    const u16* __restrict__ xf, const float* __restrict__ cw,
    const float* __restrict__ invpix, const float* __restrict__ invw,
    const float* __restrict__ mcand, const int* __restrict__ vcand,
    float* __restrict__ inp){
  __shared__ float wlds[256];
  const int q = blockIdx.x;
  const int lane = threadIdx.x;  // 0..63 = window position
  const int n = q / LPP, l = q % LPP;
  const int oy = l / OHW, ox = l % OHW;
  const int pl = (oy*3 + (lane >> 3))*HWD + (ox*3 + (lane & 7));
  const int p = n*PIXN + pl;
  float best = -1e30f; int bv = 0;
  #pragma unroll
  for (int s=0;s<4;s++){
    float v2 = mcand[(size_t)p*4 + s];
    int i2 = vcand[(size_t)p*4 + s];
    if (v2 > best || (v2 == best && i2 < bv)){ best = v2; bv = i2; }
  }
  float val = best;
  int flat = bv*64 + lane;
  #pragma unroll
  for (int off=32; off>0; off>>=1){
    float ov = __shfl_xor(val, off);
    int of = __shfl_xor(flat, off);
    if (ov > val || (ov == val && of < flat)){ val = ov; flat = of; }
  }
  const int mch = flat >> 6;
  const int pos = flat & 63;
  const float ms = val;
  // winning filter row -> LDS (exact fp32)
  *(float4*)&wlds[lane*4] = *(const float4*)&cw[(size_t)mch*CHN + lane*4];
  __syncthreads();
  // sim for this lane's pixel: dot over k from split planes (x1+x2, rel err ~2^-16)
  const int pt = p >> 4, pc = p & 15;
  float d = 0.f;
  #pragma unroll
  for (int kk=0;kk<8;kk++){
    #pragma unroll
    for (int qr=0;qr<4;qr++){
      const size_t bb = (((size_t)pt*8 + kk)*3)*512 + (qr*16 + pc)*8;
      const us8 x1 = *(const us8*)&xf[bb];
      const us8 x2 = *(const us8*)&xf[bb+512];
      #pragma unroll
      for (int j=0;j<8;j++)
        d = fmaf(bf2f(x1[j]) + bf2f(x2[j]), wlds[kk*32 + qr*8 + j], d);
    }
  }
  inp[(size_t)q*INPD + 256 + lane] = d * invpix[p] * invw[mch];
  // integ: lanes 0..31 each handle 8 channels of the winning pixel (x1+x2+x3 ~exact)
  if (lane < 32){
    const int kk = lane >> 2, qr = lane & 3;
    const int wp = n*PIXN + (oy*3 + (pos>>3))*HWD + (ox*3 + (pos&7));
    const int wpt = wp >> 4, wpc = wp & 15;
    const size_t bb = (((size_t)wpt*8 + kk)*3)*512 + (qr*16 + wpc)*8;
    const us8 x1 = *(const us8*)&xf[bb];
    const us8 x2 = *(const us8*)&xf[bb+512];
    const us8 x3 = *(const us8*)&xf[bb+1024];
    const float om = 1.0f - ms;
    const int c0 = kk*32 + qr*8;
    float4 o0, o1;
    float tv;
    tv = bf2f(x1[0])+bf2f(x2[0])+bf2f(x3[0]); o0.x = fmaf(tv, ms, wlds[c0+0]*om);
    tv = bf2f(x1[1])+bf2f(x2[1])+bf2f(x3[1]); o0.y = fmaf(tv, ms, wlds[c0+1]*om);
    tv = bf2f(x1[2])+bf2f(x2[2])+bf2f(x3[2]); o0.z = fmaf(tv, ms, wlds[c0+2]*om);
    tv = bf2f(x1[3])+bf2f(x2[3])+bf2f(x3[3]); o0.w = fmaf(tv, ms, wlds[c0+3]*om);
    tv = bf2f(x1[4])+bf2f(x2[4])+bf2f(x3[4]); o1.x = fmaf(tv, ms, wlds[c0+4]*om);
    tv = bf2f(x1[5])+bf2f(x2[5])+bf2f(x3[5]); o1.y = fmaf(tv, ms, wlds[c0+5]*om);
    tv = bf2f(x1[6])+bf2f(x2[6])+bf2f(x3[6]); o1.z = fmaf(tv, ms, wlds[c0+6]*om);
    tv = bf2f(x1[7])+bf2f(x2[7])+bf2f(x3[7]); o1.w = fmaf(tv, ms, wlds[c0+7]*om);
    *(float4*)&inp[(size_t)q*INPD + c0]     = o0;
    *(float4*)&inp[(size_t)q*INPD + c0 + 4] = o1;
  }
}

// ---------------- MLP GEMMs: C = act(A @ B^T + bias) ----------------
template<int EPI>
__global__ __launch_bounds__(256,2) void gemm_rm_k(
    const float* __restrict__ A, const float* __restrict__ B,
    const float* __restrict__ bias, float* __restrict__ C,
    int M, int N, int K){
  __shared__ __align__(16) char smem[16896];
  float (*As)[132] = (float(*)[132])smem;
  float (*Bs)[132] = (float(*)[132])(smem + 8448);
  const int t = threadIdx.x;
  const int n0 = blockIdx.x * 128;
  const int m0 = blockIdx.y * 128;
  const int tm = t & 15, tn = t >> 4;
  const int r_s = t >> 1, k_s = (t & 1) * 8;
  float4 acc[8][2];
  #pragma unroll
  for (int i=0;i<8;i++){ acc[i][0] = make_float4(0.f,0.f,0.f,0.f);
                         acc[i][1] = make_float4(0.f,0.f,0.f,0.f); }
  for (int k0 = 0; k0 < K; k0 += 16){
    float4 a4l = make_float4(0.f,0.f,0.f,0.f), a4h = a4l;
    if (m0 + r_s < M){
      a4l = *(const float4*)&A[(size_t)(m0+r_s)*K + k0 + k_s];
      a4h = *(const float4*)&A[(size_t)(m0+r_s)*K + k0 + k_s + 4];
    }
    const float4 b4l = *(const float4*)&B[(size_t)(n0+r_s)*K + k0 + k_s];
    const float4 b4h = *(const float4*)&B[(size_t)(n0+r_s)*K + k0 + k_s + 4];
    __syncthreads();
    As[k_s+0][r_s]=a4l.x; As[k_s+1][r_s]=a4l.y; As[k_s+2][r_s]=a4l.z; As[k_s+3][r_s]=a4l.w;
    As[k_s+4][r_s]=a4h.x; As[k_s+5][r_s]=a4h.y; As[k_s+6][r_s]=a4h.z; As[k_s+7][r_s]=a4h.w;
    Bs[k_s+0][r_s]=b4l.x; Bs[k_s+1][r_s]=b4l.y; Bs[k_s+2][r_s]=b4l.z; Bs[k_s+3][r_s]=b4l.w;
    Bs[k_s+4][r_s]=b4h.x; Bs[k_s+5][r_s]=b4h.y; Bs[k_s+6][r_s]=b4h.z; Bs[k_s+7][r_s]=b4h.w;
    __syncthreads();
    #pragma unroll
    for (int k=0;k<16;k++){
      const float4 al = *(const float4*)&As[k][tm*4];
      const float4 ah = *(const float4*)&As[k][64 + tm*4];
      const float4 bl = *(const float4*)&Bs[k][tn*4];
      const float4 bh = *(const float4*)&Bs[k][64 + tn*4];
      #pragma unroll
      for (int i=0;i<8;i++){
        const float ai = f4c(i<4 ? al : ah, i & 3);
        acc[i][0].x = fmaf(ai, bl.x, acc[i][0].x);
        acc[i][0].y = fmaf(ai, bl.y, acc[i][0].y);
        acc[i][0].z = fmaf(ai, bl.z, acc[i][0].z);
        acc[i][0].w = fmaf(ai, bl.w, acc[i][0].w);
        acc[i][1].x = fmaf(ai, bh.x, acc[i][1].x);
        acc[i][1].y = fmaf(ai, bh.y, acc[i][1].y);
        acc[i][1].z = fmaf(ai, bh.z, acc[i][1].z);
        acc[i][1].w = fmaf(ai, bh.w, acc[i][1].w);
      }
    }
  }
  float bb[8];
  #pragma unroll
  for (int jb=0;jb<2;jb++)
    #pragma unroll
    for (int j=0;j<4;j++) bb[jb*4+j] = bias[n0 + jb*64 + tn*4 + j];
  #pragma unroll
  for (int i=0;i<8;i++){
    const int gm = m0 + ((i<4) ? tm*4 + i : 64 + tm*4 + (i-4));
    if (gm < M){
      #pragma unroll
      for (int jb=0;jb<2;jb++){
        float4 o;
        float v0 = f4c(acc[i][jb],0) + bb[jb*4+0];
        float v1 = f4c(acc[i][jb],1) + bb[jb*4+1];
        float v2 = f4c(acc[i][jb],2) + bb[jb*4+2];
        float v3 = f4c(acc[i][jb],3) + bb[jb*4+3];
        if (EPI == 1){
          o.x = v0 > 0.f ? v0 : 0.2f*v0; o.y = v1 > 0.f ? v1 : 0.2f*v1;
          o.z = v2 > 0.f ? v2 : 0.2f*v2; o.w = v3 > 0.f ? v3 : 0.2f*v3;
        } else {
          o.x = tanhf(v0); o.y = tanhf(v1); o.z = tanhf(v2); o.w = tanhf(v3);
        }
        *(float4*)&C[(size_t)gm*N + n0 + jb*64 + tn*4] = o;
      }
    }
  }
}

extern "C" void kernel_launch(void* const* d_in, const int* in_sizes, int n_in,
                              void* d_out, int out_size, void* d_ws, size_t ws_size,
                              hipStream_t stream){
  const float* x  = (const float*)d_in[0];
  const float* cw = (const float*)d_in[1];
  const float* W1 = (const float*)d_in[2];
  const float* b1 = (const float*)d_in[3];
  const float* W2 = (const float*)d_in[4];
  const float* b2 = (const float*)d_in[5];
  float* out = (float*)d_out;
  float* ws = (float*)d_ws;
  float* invpix = ws;                                        // 73728
  float* invw   = invpix + TOTPIX;                           // 512
  float* mcand  = invw + VCN;                                // TOTPIX*4
  int*   vcand  = (int*)(mcand + (size_t)TOTPIX*4);          // TOTPIX*4
  float* inp    = (float*)(vcand + (size_t)TOTPIX*4);        // 7200*320
  float* h1     = inp + (size_t)NPATCH*INPD;                 // 7200*768
  u16*   xf     = (u16*)(h1 + (size_t)NPATCH*HID);           // TOTPIX*CHN*3 u16 (113 MB)
  u16*   wf     = xf + (size_t)TOTPIX*CHN*3;                 // VCN*CHN*3 u16
  // total ws use ~148 MB

  splitw_k<<<256,64,0,stream>>>(cw, wf);
  wnorm_k<<<2,256,0,stream>>>(cw, invw);
  pixnorm_k<<<TOTPIX/256,256,0,stream>>>(x, invpix);
  xsplit_k<<<dim3(PIXN/64, CHN/64, NB),256,0,stream>>>(x, xf);
  gemm_z_k<<<dim3(VCN/128, TOTPIX/128),256,0,stream>>>(xf, wf, invpix, invw, mcand, vcand);
  select_k<<<NPATCH,64,0,stream>>>(xf, cw, invpix, invw, mcand, vcand, inp);
  gemm_rm_k<1><<<dim3(HID/128, (NPATCH+127)/128),256,0,stream>>>(inp, W1, b1, h1, NPATCH, HID, INPD);
  gemm_rm_k<2><<<dim3(CHN/128, (NPATCH+127)/128),256,0,stream>>>(h1, W2, b2, out, NPATCH, CHN, HID);
}

// Round 6
// 538.688 us; speedup vs baseline: 1.3682x; 1.0396x over previous
//
#include <hip/hip_runtime.h>
#include <math.h>

#define NB 8
#define CHN 256
#define HWD 96
#define PIXN (HWD*HWD)        // 9216 pixels per image
#define TOTPIX (NB*PIXN)      // 73728
#define VCN 512
#define OHW 30
#define LPP (OHW*OHW)         // 900
#define NPATCH (NB*LPP)       // 7200
#define INPD 320
#define HID 768
#define MTP 456               // padded m-tile count for 7200-row operands (57*128/16)

typedef unsigned short u16;
typedef __attribute__((ext_vector_type(8))) short bf16x8;
typedef __attribute__((ext_vector_type(8))) unsigned short us8;
typedef __attribute__((ext_vector_type(4))) float f32x4;

__device__ __forceinline__ float f4c(const float4 v, int i){
  return i==0 ? v.x : i==1 ? v.y : i==2 ? v.z : v.w;
}
__device__ __forceinline__ u16 bfrn(float f){
  unsigned u = __float_as_uint(f);
  return (u16)((u + 0x7fffu + ((u>>16)&1u)) >> 16);
}
__device__ __forceinline__ float bf2f(u16 h){
  return __uint_as_float(((unsigned)h)<<16);
}

// Fragment-order split layout for X[R][K] (row-major):
//   chunk (rt, kk, s): base = ((rt*kkc + kk)*NS + s)*512, elems u16
//   chunk[lane*8+j] = split_s( X[rt*16 + (lane&15)][kk*32 + (lane>>4)*8 + j] )
// == the 16x16x32 bf16 MFMA A/B fragment: one coalesced 1KB wave load.

// ---------------- generic split kernel (cw NS=3; MLP operands NS=2) ----------------
template<int NS>
__global__ __launch_bounds__(64) void wsplit_k(const float* __restrict__ src,
                                               u16* __restrict__ dst, int K){
  const int rt = blockIdx.x, kk = blockIdx.y, kkc = gridDim.y;
  const int lane = threadIdx.x, qr = lane>>4, col = lane&15;
  const float* s = src + (size_t)(rt*16+col)*K + kk*32 + qr*8;
  us8 h1, h2, h3;
  #pragma unroll
  for (int j=0;j<8;j++){
    float a = s[j];
    u16 x1 = bfrn(a);  float r1 = a - bf2f(x1);
    u16 x2 = bfrn(r1); float r2 = r1 - bf2f(x2);
    h1[j]=x1; h2[j]=x2; h3[j]=bfrn(r2);
  }
  size_t base = ((size_t)(rt*kkc + kk)*NS)*512 + lane*8;
  *(us8*)&dst[base]     = h1;
  *(us8*)&dst[base+512] = h2;
  if (NS == 3) *(us8*)&dst[base+1024] = h3;
}

// ---------------- norms ----------------
__global__ void wnorm_k(const float* __restrict__ cw, float* __restrict__ invw){
  int v = blockIdx.x*256 + threadIdx.x;
  if (v >= VCN) return;
  const float* r = cw + (size_t)v*CHN;
  float s = 0.f;
  #pragma unroll 4
  for (int c=0;c<CHN;c++){ float t=r[c]; s = fmaf(t,t,s); }
  invw[v] = 1.0f/sqrtf(s);
}

__global__ void pixnorm_k(const float* __restrict__ x, float* __restrict__ invpix){
  int p = blockIdx.x*256 + threadIdx.x;
  if (p >= TOTPIX) return;
  int n = p / PIXN, pl = p % PIXN;
  const float* xp = x + (size_t)n*CHN*PIXN + pl;
  float s = 0.f;
  #pragma unroll 4
  for (int c=0;c<CHN;c++){ float t = xp[(size_t)c*PIXN]; s = fmaf(t,t,s); }
  invpix[p] = 1.0f/sqrtf(s);
}

// ---------------- x -> 3-split bf16, fragment order (transposing) ----------------
__global__ __launch_bounds__(256) void xsplit_k(const float* __restrict__ x,
                                                u16* __restrict__ xf){
  __shared__ float ts[64][65];
  const int p0 = blockIdx.x*64, c0 = blockIdx.y*64, img = blockIdx.z;
  const int t = threadIdx.x, lp = t&63, sub = t>>6;
  const float* xb = x + (size_t)img*CHN*PIXN;
  #pragma unroll
  for (int r=0;r<16;r++){
    int cl = r*4 + sub;
    ts[cl][lp] = xb[(size_t)(c0+cl)*PIXN + p0 + lp];
  }
  __syncthreads();
  const int w = t>>6, lane = t&63;
  const int qr = lane>>4, pcol = lane&15;
  const size_t ptg = (size_t)(img*PIXN + p0)/16 + w;
  #pragma unroll
  for (int kkl=0;kkl<2;kkl++){
    const int kkg = (c0>>5) + kkl;
    us8 h1,h2,h3;
    #pragma unroll
    for (int j=0;j<8;j++){
      float a = ts[kkl*32 + qr*8 + j][w*16 + pcol];
      u16 x1 = bfrn(a);  float r1 = a - bf2f(x1);
      u16 x2 = bfrn(r1); float r2 = r1 - bf2f(x2);
      h1[j]=x1; h2[j]=x2; h3[j]=bfrn(r2);
    }
    size_t base = ((ptg*8 + kkg)*3)*512 + lane*8;
    *(us8*)&xf[base]      = h1;
    *(us8*)&xf[base+512]  = h2;
    *(us8*)&xf[base+1024] = h3;
  }
}

// ---------------- z GEMM: barrier-free, frags direct from global ----------------
__global__ __launch_bounds__(256,2) void gemm_z_k(
    const u16* __restrict__ xf, const u16* __restrict__ wf,
    const float* __restrict__ invpix, const float* __restrict__ invw,
    float* __restrict__ mcand, int* __restrict__ vcand){
  __shared__ float rv[128][2];
  __shared__ int   ri[128][2];
  const int t = threadIdx.x;
  const int v0 = blockIdx.x*128, m0 = blockIdx.y*128;
  const int lane = t&63, wv = t>>6;
  const int mq = wv&1, nq = wv>>1;
  const int col = lane&15, qr = lane>>4;
  const size_t loff = (size_t)lane*8;
  const int ptA0 = (m0>>4) + mq*4;
  const int vtB0 = (v0>>4) + nq*4;
  f32x4 acc[4][4];
  #pragma unroll
  for (int i=0;i<4;i++)
    #pragma unroll
    for (int j=0;j<4;j++) acc[i][j] = (f32x4){0.f,0.f,0.f,0.f};

  for (int kk=0; kk<8; kk++){
    bf16x8 a[4][3];
    #pragma unroll
    for (int mi=0;mi<4;mi++){
      const size_t ab = (((size_t)(ptA0+mi)*8 + kk)*3)*512 + loff;
      a[mi][0] = *(const bf16x8*)&xf[ab];
      a[mi][1] = *(const bf16x8*)&xf[ab+512];
      a[mi][2] = *(const bf16x8*)&xf[ab+1024];
    }
    #pragma unroll
    for (int ni=0;ni<4;ni++){
      const size_t bb = (((size_t)(vtB0+ni)*8 + kk)*3)*512 + loff;
      const bf16x8 b1 = *(const bf16x8*)&wf[bb];
      const bf16x8 b2 = *(const bf16x8*)&wf[bb+512];
      const bf16x8 b3 = *(const bf16x8*)&wf[bb+1024];
      #pragma unroll
      for (int mi=0;mi<4;mi++){
        f32x4 c = acc[mi][ni];
        c = __builtin_amdgcn_mfma_f32_16x16x32_bf16(a[mi][0], b1, c, 0,0,0);
        c = __builtin_amdgcn_mfma_f32_16x16x32_bf16(a[mi][0], b2, c, 0,0,0);
        c = __builtin_amdgcn_mfma_f32_16x16x32_bf16(a[mi][1], b1, c, 0,0,0);
        c = __builtin_amdgcn_mfma_f32_16x16x32_bf16(a[mi][0], b3, c, 0,0,0);
        c = __builtin_amdgcn_mfma_f32_16x16x32_bf16(a[mi][1], b2, c, 0,0,0);
        c = __builtin_amdgcn_mfma_f32_16x16x32_bf16(a[mi][2], b1, c, 0,0,0);
        acc[mi][ni] = c;
      }
    }
  }
  float iw[4];
  #pragma unroll
  for (int ni=0; ni<4; ni++) iw[ni] = invw[v0 + nq*64 + ni*16 + col];
  #pragma unroll
  for (int mi=0; mi<4; mi++){
    #pragma unroll
    for (int r=0; r<4; r++){
      const int P = mq*64 + mi*16 + qr*4 + r;
      const float ip = invpix[m0 + P];
      float bz = -1e30f; int bvi = 0;
      #pragma unroll
      for (int ni=0; ni<4; ni++){        // ni ascending => v ascending
        const float z = f4c(*(const float4*)&acc[mi][ni], r) * ip * iw[ni];
        const int vv = v0 + nq*64 + ni*16 + col;
        if (z > bz){ bz = z; bvi = vv; }
      }
      #pragma unroll
      for (int off=1; off<16; off<<=1){
        const float oz = __shfl_xor(bz, off);
        const int  oi = __shfl_xor(bvi, off);
        if (oz > bz || (oz == bz && oi < bvi)){ bz = oz; bvi = oi; }
      }
      if (col == 0){ rv[P][nq] = bz; ri[P][nq] = bvi; }
    }
  }
  __syncthreads();
  if (t < 128){
    float z0 = rv[t][0], z1 = rv[t][1];
    int   i0 = ri[t][0], i1 = ri[t][1];
    float best = z0; int bi = i0;
    if (z1 > best || (z1 == best && i1 < bi)){ best = z1; bi = i1; }
    mcand[(size_t)(m0+t)*4 + blockIdx.x] = best;
    vcand[(size_t)(m0+t)*4 + blockIdx.x] = bi;
  }
}

// ---------------- per-patch selection, builds MLP input (7200 x 320) ----------------
__global__ __launch_bounds__(64) void select_k(
    const u16* __restrict__ xf, const float* __restrict__ cw,
    const float* __restrict__ invpix, const float* __restrict__ invw,
    const float* __restrict__ mcand, const int* __restrict__ vcand,
    float* __restrict__ inp){
  __shared__ float wlds[256];
  const int q = blockIdx.x;
  const int lane = threadIdx.x;
  const int n = q / LPP, l = q % LPP;
  const int oy = l / OHW, ox = l % OHW;
  const int pl = (oy*3 + (lane >> 3))*HWD + (ox*3 + (lane & 7));
  const int p = n*PIXN + pl;
  float best = -1e30f; int bv = 0;
  #pragma unroll
  for (int s=0;s<4;s++){
    float v2 = mcand[(size_t)p*4 + s];
    int i2 = vcand[(size_t)p*4 + s];
    if (v2 > best || (v2 == best && i2 < bv)){ best = v2; bv = i2; }
  }
  float val = best;
  int flat = bv*64 + lane;
  #pragma unroll
  for (int off=32; off>0; off>>=1){
    float ov = __shfl_xor(val, off);
    int of = __shfl_xor(flat, off);
    if (ov > val || (ov == val && of < flat)){ val = ov; flat = of; }
  }
  const int mch = flat >> 6;
  const int pos = flat & 63;
  const float ms = val;
  *(float4*)&wlds[lane*4] = *(const float4*)&cw[(size_t)mch*CHN + lane*4];
  __syncthreads();
  const int pt = p >> 4, pc = p & 15;
  float d = 0.f;
  #pragma unroll
  for (int kk=0;kk<8;kk++){
    #pragma unroll
    for (int qr=0;qr<4;qr++){
      const size_t bb = (((size_t)pt*8 + kk)*3)*512 + (qr*16 + pc)*8;
      const us8 x1 = *(const us8*)&xf[bb];
      const us8 x2 = *(const us8*)&xf[bb+512];
      #pragma unroll
      for (int j=0;j<8;j++)
        d = fmaf(bf2f(x1[j]) + bf2f(x2[j]), wlds[kk*32 + qr*8 + j], d);
    }
  }
  inp[(size_t)q*INPD + 256 + lane] = d * invpix[p] * invw[mch];
  if (lane < 32){
    const int kk = lane >> 2, qr = lane & 3;
    const int wp = n*PIXN + (oy*3 + (pos>>3))*HWD + (ox*3 + (pos&7));
    const int wpt = wp >> 4, wpc = wp & 15;
    const size_t bb = (((size_t)wpt*8 + kk)*3)*512 + (qr*16 + wpc)*8;
    const us8 x1 = *(const us8*)&xf[bb];
    const us8 x2 = *(const us8*)&xf[bb+512];
    const us8 x3 = *(const us8*)&xf[bb+1024];
    const float om = 1.0f - ms;
    const int c0 = kk*32 + qr*8;
    float4 o0, o1;
    float tv;
    tv = bf2f(x1[0])+bf2f(x2[0])+bf2f(x3[0]); o0.x = fmaf(tv, ms, wlds[c0+0]*om);
    tv = bf2f(x1[1])+bf2f(x2[1])+bf2f(x3[1]); o0.y = fmaf(tv, ms, wlds[c0+1]*om);
    tv = bf2f(x1[2])+bf2f(x2[2])+bf2f(x3[2]); o0.z = fmaf(tv, ms, wlds[c0+2]*om);
    tv = bf2f(x1[3])+bf2f(x2[3])+bf2f(x3[3]); o0.w = fmaf(tv, ms, wlds[c0+3]*om);
    tv = bf2f(x1[4])+bf2f(x2[4])+bf2f(x3[4]); o1.x = fmaf(tv, ms, wlds[c0+4]*om);
    tv = bf2f(x1[5])+bf2f(x2[5])+bf2f(x3[5]); o1.y = fmaf(tv, ms, wlds[c0+5]*om);
    tv = bf2f(x1[6])+bf2f(x2[6])+bf2f(x3[6]); o1.z = fmaf(tv, ms, wlds[c0+6]*om);
    tv = bf2f(x1[7])+bf2f(x2[7])+bf2f(x3[7]); o1.w = fmaf(tv, ms, wlds[c0+7]*om);
    *(float4*)&inp[(size_t)q*INPD + c0]     = o0;
    *(float4*)&inp[(size_t)q*INPD + c0 + 4] = o1;
  }
}

// ---------------- MLP GEMM via split-bf16 MFMA, frag-direct, barrier-free ----------
// C[m][n] = act( sum_k A[m][k] B[n][k] + bias[n] ).  A/B as 2-plane split frags.
// 3 products (a1b1, a1b2, a2b1): rel err ~2^-16. 128x128 block, 4 waves.
// EPI 1 = leaky relu, 2 = tanh. Stores guarded by m<M; A-frag loads may touch
// padded tiles (poison = tiny denormals, harmless, rows discarded).
template<int EPI>
__global__ __launch_bounds__(256,2) void mlp_k(
    const u16* __restrict__ af, const u16* __restrict__ bf,
    const float* __restrict__ bias, float* __restrict__ C,
    int M, int N, int K){
  const int kkc = K >> 5;
  const int t = threadIdx.x;
  const int n0 = blockIdx.x*128, m0 = blockIdx.y*128;
  const int lane = t&63, wv = t>>6;
  const int mq = wv&1, nq = wv>>1;
  const int col = lane&15, qr = lane>>4;
  const size_t loff = (size_t)lane*8;
  const int ptA0 = (m0>>4) + mq*4;
  const int ntB0 = (n0>>4) + nq*4;
  f32x4 acc[4][4];
  #pragma unroll
  for (int i=0;i<4;i++)
    #pragma unroll
    for (int j=0;j<4;j++) acc[i][j] = (f32x4){0.f,0.f,0.f,0.f};

  for (int kk=0; kk<kkc; kk++){
    bf16x8 a[4][2];
    #pragma unroll
    for (int mi=0;mi<4;mi++){
      const size_t ab = (((size_t)(ptA0+mi)*kkc + kk)*2)*512 + loff;
      a[mi][0] = *(const bf16x8*)&af[ab];
      a[mi][1] = *(const bf16x8*)&af[ab+512];
    }
    #pragma unroll
    for (int ni=0;ni<4;ni++){
      const size_t bb = (((size_t)(ntB0+ni)*kkc + kk)*2)*512 + loff;
      const bf16x8 b1 = *(const bf16x8*)&bf[bb];
      const bf16x8 b2 = *(const bf16x8*)&bf[bb+512];
      #pragma unroll
      for (int mi=0;mi<4;mi++){
        f32x4 c = acc[mi][ni];
        c = __builtin_amdgcn_mfma_f32_16x16x32_bf16(a[mi][0], b1, c, 0,0,0);
        c = __builtin_amdgcn_mfma_f32_16x16x32_bf16(a[mi][0], b2, c, 0,0,0);
        c = __builtin_amdgcn_mfma_f32_16x16x32_bf16(a[mi][1], b1, c, 0,0,0);
        acc[mi][ni] = c;
      }
    }
  }
  float bb4[4];
  #pragma unroll
  for (int ni=0;ni<4;ni++) bb4[ni] = bias[n0 + nq*64 + ni*16 + col];
  #pragma unroll
  for (int mi=0;mi<4;mi++){
    #pragma unroll
    for (int r=0;r<4;r++){
      const int row = m0 + mq*64 + mi*16 + qr*4 + r;
      if (row < M){
        #pragma unroll
        for (int ni=0;ni<4;ni++){
          float v = f4c(*(const float4*)&acc[mi][ni], r) + bb4[ni];
          if (EPI == 1) v = v > 0.f ? v : 0.2f*v;
          else          v = tanhf(v);
          C[(size_t)row*N + n0 + nq*64 + ni*16 + col] = v;
        }
      }
    }
  }
}

extern "C" void kernel_launch(void* const* d_in, const int* in_sizes, int n_in,
                              void* d_out, int out_size, void* d_ws, size_t ws_size,
                              hipStream_t stream){
  const float* x  = (const float*)d_in[0];
  const float* cw = (const float*)d_in[1];
  const float* W1 = (const float*)d_in[2];
  const float* b1 = (const float*)d_in[3];
  const float* W2 = (const float*)d_in[4];
  const float* b2 = (const float*)d_in[5];
  float* out = (float*)d_out;
  float* ws = (float*)d_ws;
  float* invpix = ws;                                        // 73728
  float* invw   = invpix + TOTPIX;                           // 512
  float* mcand  = invw + VCN;                                // TOTPIX*4
  int*   vcand  = (int*)(mcand + (size_t)TOTPIX*4);          // TOTPIX*4
  float* inp    = (float*)(vcand + (size_t)TOTPIX*4);        // 7200*320
  float* h1     = inp + (size_t)NPATCH*INPD;                 // 7200*768
  u16*   xf     = (u16*)(h1 + (size_t)NPATCH*HID);           // TOTPIX/16*8*3*512 (113 MB)
  u16*   wf     = xf + (size_t)(TOTPIX/16)*8*3*512;          // 32*8*3*512
  u16*   w1f    = wf + (size_t)32*8*3*512;                   // 48*10*2*512
  u16*   w2f    = w1f + (size_t)48*10*2*512;                 // 16*24*2*512
  u16*   inpf   = w2f + (size_t)16*24*2*512;                 // MTP*10*2*512 (9.3 MB)
  u16*   h1f    = inpf + (size_t)MTP*10*2*512;               // MTP*24*2*512 (22.4 MB)
  // total ws use ~182 MB

  wsplit_k<3><<<dim3(VCN/16, CHN/32),64,0,stream>>>(cw, wf, CHN);
  wsplit_k<2><<<dim3(HID/16, INPD/32),64,0,stream>>>(W1, w1f, INPD);
  wsplit_k<2><<<dim3(CHN/16, HID/32),64,0,stream>>>(W2, w2f, HID);
  wnorm_k<<<2,256,0,stream>>>(cw, invw);
  pixnorm_k<<<TOTPIX/256,256,0,stream>>>(x, invpix);
  xsplit_k<<<dim3(PIXN/64, CHN/64, NB),256,0,stream>>>(x, xf);
  gemm_z_k<<<dim3(VCN/128, TOTPIX/128),256,0,stream>>>(xf, wf, invpix, invw, mcand, vcand);
  select_k<<<NPATCH,64,0,stream>>>(xf, cw, invpix, invw, mcand, vcand, inp);
  wsplit_k<2><<<dim3(NPATCH/16, INPD/32),64,0,stream>>>(inp, inpf, INPD);
  mlp_k<1><<<dim3(HID/128, (NPATCH+127)/128),256,0,stream>>>(inpf, w1f, b1, h1, NPATCH, HID, INPD);
  wsplit_k<2><<<dim3(NPATCH/16, HID/32),64,0,stream>>>(h1, h1f, HID);
  mlp_k<2><<<dim3(CHN/128, (NPATCH+127)/128),256,0,stream>>>(h1f, w2f, b2, out, NPATCH, CHN, HID);
}

// Round 7
// 452.291 us; speedup vs baseline: 1.6295x; 1.1910x over previous
//
#include <hip/hip_runtime.h>
#include <hip/hip_fp16.h>
#include <math.h>

#define NB 8
#define CHN 256
#define HWD 96
#define PIXN (HWD*HWD)        // 9216 pixels per image
#define TOTPIX (NB*PIXN)      // 73728
#define VCN 512
#define OHW 30
#define LPP (OHW*OHW)         // 900
#define NPATCH (NB*LPP)       // 7200
#define INPD 320
#define HID 768
#define MTP 456               // padded m-tile count for 7200-row operands (57*128/16)

typedef unsigned short u16;
typedef __attribute__((ext_vector_type(8))) short bf16x8;
typedef __attribute__((ext_vector_type(8))) unsigned short us8;
typedef __attribute__((ext_vector_type(4))) float f32x4;

__device__ __forceinline__ float f4c(const float4 v, int i){
  return i==0 ? v.x : i==1 ? v.y : i==2 ? v.z : v.w;
}
__device__ __forceinline__ u16 bfrn(float f){
  unsigned u = __float_as_uint(f);
  return (u16)((u + 0x7fffu + ((u>>16)&1u)) >> 16);
}
__device__ __forceinline__ float bf2f(u16 h){
  return __uint_as_float(((unsigned)h)<<16);
}

// Fragment-order split layout for X[R][K] (row-major):
//   chunk (rt, kk, s): base = ((rt*kkc + kk)*NS + s)*512, elems u16
//   chunk[lane*8+j] = split_s( X[rt*16 + (lane&15)][kk*32 + (lane>>4)*8 + j] )
// == the 16x16x32 bf16 MFMA A/B fragment: one coalesced 1KB wave load.

// ---------------- generic split kernel (cw NS=3; MLP operands NS=2) ----------------
template<int NS>
__global__ __launch_bounds__(64) void wsplit_k(const float* __restrict__ src,
                                               u16* __restrict__ dst, int K){
  const int rt = blockIdx.x, kk = blockIdx.y, kkc = gridDim.y;
  const int lane = threadIdx.x, qr = lane>>4, col = lane&15;
  const float* s = src + (size_t)(rt*16+col)*K + kk*32 + qr*8;
  us8 h1, h2, h3;
  #pragma unroll
  for (int j=0;j<8;j++){
    float a = s[j];
    u16 x1 = bfrn(a);  float r1 = a - bf2f(x1);
    u16 x2 = bfrn(r1); float r2 = r1 - bf2f(x2);
    h1[j]=x1; h2[j]=x2; h3[j]=bfrn(r2);
  }
  size_t base = ((size_t)(rt*kkc + kk)*NS)*512 + lane*8;
  *(us8*)&dst[base]     = h1;
  *(us8*)&dst[base+512] = h2;
  if (NS == 3) *(us8*)&dst[base+1024] = h3;
}

// ---------------- norms ----------------
__global__ void wnorm_k(const float* __restrict__ cw, float* __restrict__ invw){
  int v = blockIdx.x*256 + threadIdx.x;
  if (v >= VCN) return;
  const float* r = cw + (size_t)v*CHN;
  float s = 0.f;
  #pragma unroll 4
  for (int c=0;c<CHN;c++){ float t=r[c]; s = fmaf(t,t,s); }
  invw[v] = 1.0f/sqrtf(s);
}

__global__ void pixnorm_k(const float* __restrict__ x, float* __restrict__ invpix){
  int p = blockIdx.x*256 + threadIdx.x;
  if (p >= TOTPIX) return;
  int n = p / PIXN, pl = p % PIXN;
  const float* xp = x + (size_t)n*CHN*PIXN + pl;
  float s = 0.f;
  #pragma unroll 4
  for (int c=0;c<CHN;c++){ float t = xp[(size_t)c*PIXN]; s = fmaf(t,t,s); }
  invpix[p] = 1.0f/sqrtf(s);
}

// ---------------- x -> 3-split bf16, fragment order (transposing) ----------------
__global__ __launch_bounds__(256) void xsplit_k(const float* __restrict__ x,
                                                u16* __restrict__ xf){
  __shared__ float ts[64][65];
  const int p0 = blockIdx.x*64, c0 = blockIdx.y*64, img = blockIdx.z;
  const int t = threadIdx.x, lp = t&63, sub = t>>6;
  const float* xb = x + (size_t)img*CHN*PIXN;
  #pragma unroll
  for (int r=0;r<16;r++){
    int cl = r*4 + sub;
    ts[cl][lp] = xb[(size_t)(c0+cl)*PIXN + p0 + lp];
  }
  __syncthreads();
  const int w = t>>6, lane = t&63;
  const int qr = lane>>4, pcol = lane&15;
  const size_t ptg = (size_t)(img*PIXN + p0)/16 + w;
  #pragma unroll
  for (int kkl=0;kkl<2;kkl++){
    const int kkg = (c0>>5) + kkl;
    us8 h1,h2,h3;
    #pragma unroll
    for (int j=0;j<8;j++){
      float a = ts[kkl*32 + qr*8 + j][w*16 + pcol];
      u16 x1 = bfrn(a);  float r1 = a - bf2f(x1);
      u16 x2 = bfrn(r1); float r2 = r1 - bf2f(x2);
      h1[j]=x1; h2[j]=x2; h3[j]=bfrn(r2);
    }
    size_t base = ((ptg*8 + kkg)*3)*512 + lane*8;
    *(us8*)&xf[base]      = h1;
    *(us8*)&xf[base+512]  = h2;
    *(us8*)&xf[base+1024] = h3;
  }
}

// ---------------- z GEMM: barrier-free, frags direct from global ----------------
// Epilogue now also stores the full normalized sim map zf[p][v] (fp16) so
// select_k can gather instead of recomputing dots (saves ~460 MB of reads).
__global__ __launch_bounds__(256,2) void gemm_z_k(
    const u16* __restrict__ xf, const u16* __restrict__ wf,
    const float* __restrict__ invpix, const float* __restrict__ invw,
    float* __restrict__ mcand, int* __restrict__ vcand,
    __half* __restrict__ zf){
  __shared__ float rv[128][2];
  __shared__ int   ri[128][2];
  const int t = threadIdx.x;
  const int v0 = blockIdx.x*128, m0 = blockIdx.y*128;
  const int lane = t&63, wv = t>>6;
  const int mq = wv&1, nq = wv>>1;
  const int col = lane&15, qr = lane>>4;
  const size_t loff = (size_t)lane*8;
  const int ptA0 = (m0>>4) + mq*4;
  const int vtB0 = (v0>>4) + nq*4;
  f32x4 acc[4][4];
  #pragma unroll
  for (int i=0;i<4;i++)
    #pragma unroll
    for (int j=0;j<4;j++) acc[i][j] = (f32x4){0.f,0.f,0.f,0.f};

  for (int kk=0; kk<8; kk++){
    bf16x8 a[4][3];
    #pragma unroll
    for (int mi=0;mi<4;mi++){
      const size_t ab = (((size_t)(ptA0+mi)*8 + kk)*3)*512 + loff;
      a[mi][0] = *(const bf16x8*)&xf[ab];
      a[mi][1] = *(const bf16x8*)&xf[ab+512];
      a[mi][2] = *(const bf16x8*)&xf[ab+1024];
    }
    #pragma unroll
    for (int ni=0;ni<4;ni++){
      const size_t bb = (((size_t)(vtB0+ni)*8 + kk)*3)*512 + loff;
      const bf16x8 b1 = *(const bf16x8*)&wf[bb];
      const bf16x8 b2 = *(const bf16x8*)&wf[bb+512];
      const bf16x8 b3 = *(const bf16x8*)&wf[bb+1024];
      #pragma unroll
      for (int mi=0;mi<4;mi++){
        f32x4 c = acc[mi][ni];
        c = __builtin_amdgcn_mfma_f32_16x16x32_bf16(a[mi][0], b1, c, 0,0,0);
        c = __builtin_amdgcn_mfma_f32_16x16x32_bf16(a[mi][0], b2, c, 0,0,0);
        c = __builtin_amdgcn_mfma_f32_16x16x32_bf16(a[mi][1], b1, c, 0,0,0);
        c = __builtin_amdgcn_mfma_f32_16x16x32_bf16(a[mi][0], b3, c, 0,0,0);
        c = __builtin_amdgcn_mfma_f32_16x16x32_bf16(a[mi][1], b2, c, 0,0,0);
        c = __builtin_amdgcn_mfma_f32_16x16x32_bf16(a[mi][2], b1, c, 0,0,0);
        acc[mi][ni] = c;
      }
    }
  }
  float iw[4];
  #pragma unroll
  for (int ni=0; ni<4; ni++) iw[ni] = invw[v0 + nq*64 + ni*16 + col];
  #pragma unroll
  for (int mi=0; mi<4; mi++){
    #pragma unroll
    for (int r=0; r<4; r++){
      const int P = mq*64 + mi*16 + qr*4 + r;
      const float ip = invpix[m0 + P];
      float bz = -1e30f; int bvi = 0;
      #pragma unroll
      for (int ni=0; ni<4; ni++){        // ni ascending => v ascending
        const float z = f4c(*(const float4*)&acc[mi][ni], r) * ip * iw[ni];
        const int vv = v0 + nq*64 + ni*16 + col;
        zf[(size_t)(m0+P)*VCN + vv] = __float2half(z);
        if (z > bz){ bz = z; bvi = vv; }
      }
      #pragma unroll
      for (int off=1; off<16; off<<=1){
        const float oz = __shfl_xor(bz, off);
        const int  oi = __shfl_xor(bvi, off);
        if (oz > bz || (oz == bz && oi < bvi)){ bz = oz; bvi = oi; }
      }
      if (col == 0){ rv[P][nq] = bz; ri[P][nq] = bvi; }
    }
  }
  __syncthreads();
  if (t < 128){
    float z0 = rv[t][0], z1 = rv[t][1];
    int   i0 = ri[t][0], i1 = ri[t][1];
    float best = z0; int bi = i0;
    if (z1 > best || (z1 == best && i1 < bi)){ best = z1; bi = i1; }
    mcand[(size_t)(m0+t)*4 + blockIdx.x] = best;
    vcand[(size_t)(m0+t)*4 + blockIdx.x] = bi;
  }
}

// ---------------- per-patch selection, builds MLP input (7200 x 320) ----------------
// sim gathered from zf (one fp16 per lane) instead of recomputed dots.
__global__ __launch_bounds__(64) void select_k(
    const u16* __restrict__ xf, const float* __restrict__ cw,
    const __half* __restrict__ zf,
    const float* __restrict__ mcand, const int* __restrict__ vcand,
    float* __restrict__ inp){
  __shared__ float wlds[256];
  const int q = blockIdx.x;
  const int lane = threadIdx.x;
  const int n = q / LPP, l = q % LPP;
  const int oy = l / OHW, ox = l % OHW;
  const int pl = (oy*3 + (lane >> 3))*HWD + (ox*3 + (lane & 7));
  const int p = n*PIXN + pl;
  float best = -1e30f; int bv = 0;
  #pragma unroll
  for (int s=0;s<4;s++){
    float v2 = mcand[(size_t)p*4 + s];
    int i2 = vcand[(size_t)p*4 + s];
    if (v2 > best || (v2 == best && i2 < bv)){ best = v2; bv = i2; }
  }
  float val = best;
  int flat = bv*64 + lane;
  #pragma unroll
  for (int off=32; off>0; off>>=1){
    float ov = __shfl_xor(val, off);
    int of = __shfl_xor(flat, off);
    if (ov > val || (ov == val && of < flat)){ val = ov; flat = of; }
  }
  const int mch = flat >> 6;
  const int pos = flat & 63;
  const float ms = val;
  *(float4*)&wlds[lane*4] = *(const float4*)&cw[(size_t)mch*CHN + lane*4];
  __syncthreads();
  // sim_map: gather this lane's pixel-vs-winning-filter sim from the z map
  inp[(size_t)q*INPD + 256 + lane] = __half2float(zf[(size_t)p*VCN + mch]);
  // integ: lanes 0..31 handle 8 channels of the winning pixel (x1+x2+x3 ~exact)
  if (lane < 32){
    const int kk = lane >> 2, qr = lane & 3;
    const int wp = n*PIXN + (oy*3 + (pos>>3))*HWD + (ox*3 + (pos&7));
    const int wpt = wp >> 4, wpc = wp & 15;
    const size_t bb = (((size_t)wpt*8 + kk)*3)*512 + (qr*16 + wpc)*8;
    const us8 x1 = *(const us8*)&xf[bb];
    const us8 x2 = *(const us8*)&xf[bb+512];
    const us8 x3 = *(const us8*)&xf[bb+1024];
    const float om = 1.0f - ms;
    const int c0 = kk*32 + qr*8;
    float4 o0, o1;
    float tv;
    tv = bf2f(x1[0])+bf2f(x2[0])+bf2f(x3[0]); o0.x = fmaf(tv, ms, wlds[c0+0]*om);
    tv = bf2f(x1[1])+bf2f(x2[1])+bf2f(x3[1]); o0.y = fmaf(tv, ms, wlds[c0+1]*om);
    tv = bf2f(x1[2])+bf2f(x2[2])+bf2f(x3[2]); o0.z = fmaf(tv, ms, wlds[c0+2]*om);
    tv = bf2f(x1[3])+bf2f(x2[3])+bf2f(x3[3]); o0.w = fmaf(tv, ms, wlds[c0+3]*om);
    tv = bf2f(x1[4])+bf2f(x2[4])+bf2f(x3[4]); o1.x = fmaf(tv, ms, wlds[c0+4]*om);
    tv = bf2f(x1[5])+bf2f(x2[5])+bf2f(x3[5]); o1.y = fmaf(tv, ms, wlds[c0+5]*om);
    tv = bf2f(x1[6])+bf2f(x2[6])+bf2f(x3[6]); o1.z = fmaf(tv, ms, wlds[c0+6]*om);
    tv = bf2f(x1[7])+bf2f(x2[7])+bf2f(x3[7]); o1.w = fmaf(tv, ms, wlds[c0+7]*om);
    *(float4*)&inp[(size_t)q*INPD + c0]     = o0;
    *(float4*)&inp[(size_t)q*INPD + c0 + 4] = o1;
  }
}

// ---------------- MLP GEMM via split-bf16 MFMA, frag-direct, barrier-free ----------
template<int EPI>
__global__ __launch_bounds__(256,2) void mlp_k(
    const u16* __restrict__ af, const u16* __restrict__ bf,
    const float* __restrict__ bias, float* __restrict__ C,
    int M, int N, int K){
  const int kkc = K >> 5;
  const int t = threadIdx.x;
  const int n0 = blockIdx.x*128, m0 = blockIdx.y*128;
  const int lane = t&63, wv = t>>6;
  const int mq = wv&1, nq = wv>>1;
  const int col = lane&15, qr = lane>>4;
  const size_t loff = (size_t)lane*8;
  const int ptA0 = (m0>>4) + mq*4;
  const int ntB0 = (n0>>4) + nq*4;
  f32x4 acc[4][4];
  #pragma unroll
  for (int i=0;i<4;i++)
    #pragma unroll
    for (int j=0;j<4;j++) acc[i][j] = (f32x4){0.f,0.f,0.f,0.f};

  for (int kk=0; kk<kkc; kk++){
    bf16x8 a[4][2];
    #pragma unroll
    for (int mi=0;mi<4;mi++){
      const size_t ab = (((size_t)(ptA0+mi)*kkc + kk)*2)*512 + loff;
      a[mi][0] = *(const bf16x8*)&af[ab];
      a[mi][1] = *(const bf16x8*)&af[ab+512];
    }
    #pragma unroll
    for (int ni=0;ni<4;ni++){
      const size_t bb = (((size_t)(ntB0+ni)*kkc + kk)*2)*512 + loff;
      const bf16x8 b1 = *(const bf16x8*)&bf[bb];
      const bf16x8 b2 = *(const bf16x8*)&bf[bb+512];
      #pragma unroll
      for (int mi=0;mi<4;mi++){
        f32x4 c = acc[mi][ni];
        c = __builtin_amdgcn_mfma_f32_16x16x32_bf16(a[mi][0], b1, c, 0,0,0);
        c = __builtin_amdgcn_mfma_f32_16x16x32_bf16(a[mi][0], b2, c, 0,0,0);
        c = __builtin_amdgcn_mfma_f32_16x16x32_bf16(a[mi][1], b1, c, 0,0,0);
        acc[mi][ni] = c;
      }
    }
  }
  float bb4[4];
  #pragma unroll
  for (int ni=0;ni<4;ni++) bb4[ni] = bias[n0 + nq*64 + ni*16 + col];
  #pragma unroll
  for (int mi=0;mi<4;mi++){
    #pragma unroll
    for (int r=0;r<4;r++){
      const int row = m0 + mq*64 + mi*16 + qr*4 + r;
      if (row < M){
        #pragma unroll
        for (int ni=0;ni<4;ni++){
          float v = f4c(*(const float4*)&acc[mi][ni], r) + bb4[ni];
          if (EPI == 1) v = v > 0.f ? v : 0.2f*v;
          else          v = tanhf(v);
          C[(size_t)row*N + n0 + nq*64 + ni*16 + col] = v;
        }
      }
    }
  }
}

extern "C" void kernel_launch(void* const* d_in, const int* in_sizes, int n_in,
                              void* d_out, int out_size, void* d_ws, size_t ws_size,
                              hipStream_t stream){
  const float* x  = (const float*)d_in[0];
  const float* cw = (const float*)d_in[1];
  const float* W1 = (const float*)d_in[2];
  const float* b1 = (const float*)d_in[3];
  const float* W2 = (const float*)d_in[4];
  const float* b2 = (const float*)d_in[5];
  float* out = (float*)d_out;
  float* ws = (float*)d_ws;
  float* invpix = ws;                                        // 73728
  float* invw   = invpix + TOTPIX;                           // 512
  float* mcand  = invw + VCN;                                // TOTPIX*4
  int*   vcand  = (int*)(mcand + (size_t)TOTPIX*4);          // TOTPIX*4
  float* inp    = (float*)(vcand + (size_t)TOTPIX*4);        // 7200*320
  float* h1     = inp + (size_t)NPATCH*INPD;                 // 7200*768
  u16*   xf     = (u16*)(h1 + (size_t)NPATCH*HID);           // 113.2 MB
  u16*   wf     = xf + (size_t)(TOTPIX/16)*8*3*512;
  u16*   w1f    = wf + (size_t)32*8*3*512;
  u16*   w2f    = w1f + (size_t)48*10*2*512;
  // zf (75.5 MB, fp16) aliases the inpf/h1f region: zf is dead once select_k
  // finishes, and inpf/h1f are only written after select_k (stream-ordered).
  __half* zf    = (__half*)(w2f + (size_t)16*24*2*512);      // TOTPIX*VCN half
  u16*   inpf   = (u16*)zf;                                  // MTP*10*2*512
  u16*   h1f    = inpf + (size_t)MTP*10*2*512;               // MTP*24*2*512
  // total ws use ~225 MB

  wsplit_k<3><<<dim3(VCN/16, CHN/32),64,0,stream>>>(cw, wf, CHN);
  wsplit_k<2><<<dim3(HID/16, INPD/32),64,0,stream>>>(W1, w1f, INPD);
  wsplit_k<2><<<dim3(CHN/16, HID/32),64,0,stream>>>(W2, w2f, HID);
  wnorm_k<<<2,256,0,stream>>>(cw, invw);
  pixnorm_k<<<TOTPIX/256,256,0,stream>>>(x, invpix);
  xsplit_k<<<dim3(PIXN/64, CHN/64, NB),256,0,stream>>>(x, xf);
  gemm_z_k<<<dim3(VCN/128, TOTPIX/128),256,0,stream>>>(xf, wf, invpix, invw, mcand, vcand, zf);
  select_k<<<NPATCH,64,0,stream>>>(xf, cw, zf, mcand, vcand, inp);
  wsplit_k<2><<<dim3(NPATCH/16, INPD/32),64,0,stream>>>(inp, inpf, INPD);
  mlp_k<1><<<dim3(HID/128, (NPATCH+127)/128),256,0,stream>>>(inpf, w1f, b1, h1, NPATCH, HID, INPD);
  wsplit_k<2><<<dim3(NPATCH/16, HID/32),64,0,stream>>>(h1, h1f, HID);
  mlp_k<2><<<dim3(CHN/128, (NPATCH+127)/128),256,0,stream>>>(h1f, w2f, b2, out, NPATCH, CHN, HID);
}

// Round 8
// 369.310 us; speedup vs baseline: 1.9957x; 1.2247x over previous
//
#include <hip/hip_runtime.h>
#include <hip/hip_fp16.h>
#include <math.h>

#define NB 8
#define CHN 256
#define HWD 96
#define PIXN (HWD*HWD)        // 9216 pixels per image
#define TOTPIX (NB*PIXN)      // 73728
#define VCN 512
#define OHW 30
#define LPP (OHW*OHW)         // 900
#define NPATCH (NB*LPP)       // 7200
#define INPD 320
#define HID 768
#define MTP 456               // padded m-tile count for 7200-row operands (57*128/16)

typedef unsigned short u16;
typedef __attribute__((ext_vector_type(8))) short bf16x8;
typedef __attribute__((ext_vector_type(8))) unsigned short us8;
typedef __attribute__((ext_vector_type(4))) float f32x4;

__device__ __forceinline__ float f4c(const float4 v, int i){
  return i==0 ? v.x : i==1 ? v.y : i==2 ? v.z : v.w;
}
__device__ __forceinline__ u16 bfrn(float f){
  unsigned u = __float_as_uint(f);
  return (u16)((u + 0x7fffu + ((u>>16)&1u)) >> 16);
}
__device__ __forceinline__ float bf2f(u16 h){
  return __uint_as_float(((unsigned)h)<<16);
}

// Fragment-order split layout for X[R][K] (row-major):
//   chunk (rt, kk, s): base = ((rt*kkc + kk)*NS + s)*512, u16 elems
//   chunk[lane*8+j] = split_s( X[rt*16 + (lane&15)][kk*32 + (lane>>4)*8 + j] )
// == the 16x16x32 bf16 MFMA A/B fragment: one coalesced 1KB wave load.

// ---------------- generic split kernel (weights only now) ----------------
template<int NS>
__global__ __launch_bounds__(64) void wsplit_k(const float* __restrict__ src,
                                               u16* __restrict__ dst, int K){
  const int rt = blockIdx.x, kk = blockIdx.y, kkc = gridDim.y;
  const int lane = threadIdx.x, qr = lane>>4, col = lane&15;
  const float* s = src + (size_t)(rt*16+col)*K + kk*32 + qr*8;
  us8 h1, h2, h3;
  #pragma unroll
  for (int j=0;j<8;j++){
    float a = s[j];
    u16 x1 = bfrn(a);  float r1 = a - bf2f(x1);
    u16 x2 = bfrn(r1); float r2 = r1 - bf2f(x2);
    h1[j]=x1; h2[j]=x2; h3[j]=bfrn(r2);
  }
  size_t base = ((size_t)(rt*kkc + kk)*NS)*512 + lane*8;
  *(us8*)&dst[base]     = h1;
  *(us8*)&dst[base+512] = h2;
  if (NS == 3) *(us8*)&dst[base+1024] = h3;
}

// ---------------- norms ----------------
__global__ void wnorm_k(const float* __restrict__ cw, float* __restrict__ invw){
  int v = blockIdx.x*256 + threadIdx.x;
  if (v >= VCN) return;
  const float* r = cw + (size_t)v*CHN;
  float s = 0.f;
  #pragma unroll 4
  for (int c=0;c<CHN;c++){ float t=r[c]; s = fmaf(t,t,s); }
  invw[v] = 1.0f/sqrtf(s);
}

__global__ void pixfin_k(const float* __restrict__ sumsq, float* __restrict__ invpix){
  int p = blockIdx.x*256 + threadIdx.x;
  if (p < TOTPIX) invpix[p] = rsqrtf(sumsq[p]);
}

// ---------------- x -> 3-split bf16 frag order + fused pixel sumsq ----------------
__global__ __launch_bounds__(256) void xsplit_k(const float* __restrict__ x,
                                                u16* __restrict__ xf,
                                                float* __restrict__ sumsq){
  __shared__ float ts[64][65];
  __shared__ float ssq[64];
  const int p0 = blockIdx.x*64, c0 = blockIdx.y*64, img = blockIdx.z;
  const int t = threadIdx.x, lp = t&63, sub = t>>6;
  if (t < 64) ssq[t] = 0.f;
  const float* xb = x + (size_t)img*CHN*PIXN;
  #pragma unroll
  for (int r=0;r<16;r++){
    int cl = r*4 + sub;
    ts[cl][lp] = xb[(size_t)(c0+cl)*PIXN + p0 + lp];
  }
  __syncthreads();
  // partial sum of squares over this block's 64 channels for pixel lp
  {
    float s = 0.f;
    #pragma unroll
    for (int r=0;r<16;r++){ float v = ts[r*4+sub][lp]; s = fmaf(v,v,s); }
    atomicAdd(&ssq[lp], s);
  }
  const int w = t>>6, lane = t&63;
  const int qr = lane>>4, pcol = lane&15;
  const size_t ptg = (size_t)(img*PIXN + p0)/16 + w;
  #pragma unroll
  for (int kkl=0;kkl<2;kkl++){
    const int kkg = (c0>>5) + kkl;
    us8 h1,h2,h3;
    #pragma unroll
    for (int j=0;j<8;j++){
      float a = ts[kkl*32 + qr*8 + j][w*16 + pcol];
      u16 x1 = bfrn(a);  float r1 = a - bf2f(x1);
      u16 x2 = bfrn(r1); float r2 = r1 - bf2f(x2);
      h1[j]=x1; h2[j]=x2; h3[j]=bfrn(r2);
    }
    size_t base = ((ptg*8 + kkg)*3)*512 + lane*8;
    *(us8*)&xf[base]      = h1;
    *(us8*)&xf[base+512]  = h2;
    *(us8*)&xf[base+1024] = h3;
  }
  __syncthreads();
  if (t < 64) atomicAdd(&sumsq[(size_t)img*PIXN + p0 + t], ssq[t]);
}

// ---------------- z GEMM: barrier-free, frags direct from global ----------------
__global__ __launch_bounds__(256,4) void gemm_z_k(
    const u16* __restrict__ xf, const u16* __restrict__ wf,
    const float* __restrict__ invpix, const float* __restrict__ invw,
    float* __restrict__ mcand, int* __restrict__ vcand,
    __half* __restrict__ zf){
  __shared__ float rv[128][2];
  __shared__ int   ri[128][2];
  const int t = threadIdx.x;
  const int v0 = blockIdx.x*128, m0 = blockIdx.y*128;
  const int lane = t&63, wv = t>>6;
  const int mq = wv&1, nq = wv>>1;
  const int col = lane&15, qr = lane>>4;
  const size_t loff = (size_t)lane*8;
  const int ptA0 = (m0>>4) + mq*4;
  const int vtB0 = (v0>>4) + nq*4;
  f32x4 acc[4][4];
  #pragma unroll
  for (int i=0;i<4;i++)
    #pragma unroll
    for (int j=0;j<4;j++) acc[i][j] = (f32x4){0.f,0.f,0.f,0.f};

  for (int kk=0; kk<8; kk++){
    bf16x8 a[4][3];
    #pragma unroll
    for (int mi=0;mi<4;mi++){
      const size_t ab = (((size_t)(ptA0+mi)*8 + kk)*3)*512 + loff;
      a[mi][0] = *(const bf16x8*)&xf[ab];
      a[mi][1] = *(const bf16x8*)&xf[ab+512];
      a[mi][2] = *(const bf16x8*)&xf[ab+1024];
    }
    #pragma unroll
    for (int ni=0;ni<4;ni++){
      const size_t bb = (((size_t)(vtB0+ni)*8 + kk)*3)*512 + loff;
      const bf16x8 b1 = *(const bf16x8*)&wf[bb];
      const bf16x8 b2 = *(const bf16x8*)&wf[bb+512];
      const bf16x8 b3 = *(const bf16x8*)&wf[bb+1024];
      #pragma unroll
      for (int mi=0;mi<4;mi++){
        f32x4 c = acc[mi][ni];
        c = __builtin_amdgcn_mfma_f32_16x16x32_bf16(a[mi][0], b1, c, 0,0,0);
        c = __builtin_amdgcn_mfma_f32_16x16x32_bf16(a[mi][0], b2, c, 0,0,0);
        c = __builtin_amdgcn_mfma_f32_16x16x32_bf16(a[mi][1], b1, c, 0,0,0);
        c = __builtin_amdgcn_mfma_f32_16x16x32_bf16(a[mi][0], b3, c, 0,0,0);
        c = __builtin_amdgcn_mfma_f32_16x16x32_bf16(a[mi][1], b2, c, 0,0,0);
        c = __builtin_amdgcn_mfma_f32_16x16x32_bf16(a[mi][2], b1, c, 0,0,0);
        acc[mi][ni] = c;
      }
    }
  }
  float iw[4];
  #pragma unroll
  for (int ni=0; ni<4; ni++) iw[ni] = invw[v0 + nq*64 + ni*16 + col];
  #pragma unroll
  for (int mi=0; mi<4; mi++){
    #pragma unroll
    for (int r=0; r<4; r++){
      const int P = mq*64 + mi*16 + qr*4 + r;
      const float ip = invpix[m0 + P];
      float bz = -1e30f; int bvi = 0;
      #pragma unroll
      for (int ni=0; ni<4; ni++){        // ni ascending => v ascending
        const float z = f4c(*(const float4*)&acc[mi][ni], r) * ip * iw[ni];
        const int vv = v0 + nq*64 + ni*16 + col;
        zf[(size_t)(m0+P)*VCN + vv] = __float2half(z);
        if (z > bz){ bz = z; bvi = vv; }
      }
      #pragma unroll
      for (int off=1; off<16; off<<=1){
        const float oz = __shfl_xor(bz, off);
        const int  oi = __shfl_xor(bvi, off);
        if (oz > bz || (oz == bz && oi < bvi)){ bz = oz; bvi = oi; }
      }
      if (col == 0){ rv[P][nq] = bz; ri[P][nq] = bvi; }
    }
  }
  __syncthreads();
  if (t < 128){
    float z0 = rv[t][0], z1 = rv[t][1];
    int   i0 = ri[t][0], i1 = ri[t][1];
    float best = z0; int bi = i0;
    if (z1 > best || (z1 == best && i1 < bi)){ best = z1; bi = i1; }
    mcand[(size_t)(m0+t)*4 + blockIdx.x] = best;
    vcand[(size_t)(m0+t)*4 + blockIdx.x] = bi;
  }
}

// ---------------- per-patch selection -> inpf split-frag directly ----------------
// inpf: 2-split frag layout, R=NPATCH rows (rt=q>>4), kkc=10.
__global__ __launch_bounds__(64) void select_k(
    const u16* __restrict__ xf, const float* __restrict__ cw,
    const __half* __restrict__ zf,
    const float* __restrict__ mcand, const int* __restrict__ vcand,
    u16* __restrict__ inpf){
  __shared__ float wlds[256];
  __shared__ float simv[64];
  const int q = blockIdx.x;
  const int lane = threadIdx.x;
  const int n = q / LPP, l = q % LPP;
  const int oy = l / OHW, ox = l % OHW;
  const int pl = (oy*3 + (lane >> 3))*HWD + (ox*3 + (lane & 7));
  const int p = n*PIXN + pl;
  const int rt = q >> 4, ql = q & 15;
  float best = -1e30f; int bv = 0;
  #pragma unroll
  for (int s=0;s<4;s++){
    float v2 = mcand[(size_t)p*4 + s];
    int i2 = vcand[(size_t)p*4 + s];
    if (v2 > best || (v2 == best && i2 < bv)){ best = v2; bv = i2; }
  }
  float val = best;
  int flat = bv*64 + lane;
  #pragma unroll
  for (int off=32; off>0; off>>=1){
    float ov = __shfl_xor(val, off);
    int of = __shfl_xor(flat, off);
    if (ov > val || (ov == val && of < flat)){ val = ov; flat = of; }
  }
  const int mch = flat >> 6;
  const int pos = flat & 63;
  const float ms = val;
  *(float4*)&wlds[lane*4] = *(const float4*)&cw[(size_t)mch*CHN + lane*4];
  simv[lane] = __half2float(zf[(size_t)p*VCN + mch]);
  __syncthreads();
  // integ: lanes 0..31 handle channels c0..c0+7 (one us8 chunk per split)
  if (lane < 32){
    const int kk = lane >> 2, qr = lane & 3;
    const int wp = n*PIXN + (oy*3 + (pos>>3))*HWD + (ox*3 + (pos&7));
    const int wpt = wp >> 4, wpc = wp & 15;
    const size_t bb = (((size_t)wpt*8 + kk)*3)*512 + (qr*16 + wpc)*8;
    const us8 x1 = *(const us8*)&xf[bb];
    const us8 x2 = *(const us8*)&xf[bb+512];
    const us8 x3 = *(const us8*)&xf[bb+1024];
    const float om = 1.0f - ms;
    const int c0 = kk*32 + qr*8;
    us8 p1, p2;
    #pragma unroll
    for (int j=0;j<8;j++){
      float tv = bf2f(x1[j])+bf2f(x2[j])+bf2f(x3[j]);
      float v = fmaf(tv, ms, wlds[c0+j]*om);
      u16 s1 = bfrn(v);
      p1[j] = s1; p2[j] = bfrn(v - bf2f(s1));
    }
    const size_t ob = ((size_t)(rt*10 + kk)*2)*512 + (qr*16 + ql)*8;
    *(us8*)&inpf[ob]     = p1;
    *(us8*)&inpf[ob+512] = p2;
  }
  // sims: channels 256..319 -> chunks kk in {8,9}; 16 tasks = (s, kk, qr)
  if (lane < 16){
    const int s = lane >> 3, kk = 8 + ((lane >> 2) & 1), qr = lane & 3;
    us8 pv;
    #pragma unroll
    for (int j=0;j<8;j++){
      float v = simv[(kk-8)*32 + qr*8 + j];
      u16 s1 = bfrn(v);
      pv[j] = (s == 0) ? s1 : bfrn(v - bf2f(s1));
    }
    const size_t ob = ((size_t)(rt*10 + kk)*2 + s)*512 + (qr*16 + ql)*8;
    *(us8*)&inpf[ob] = pv;
  }
}

// ---------------- MLP layer 1: split-frag in, split-frag out (h1f) ----------------
__global__ __launch_bounds__(256,2) void mlp1_k(
    const u16* __restrict__ af, const u16* __restrict__ bf,
    const float* __restrict__ bias, u16* __restrict__ h1f){
  const int kkc = INPD >> 5;     // 10
  const int t = threadIdx.x;
  const int n0 = blockIdx.x*128, m0 = blockIdx.y*128;
  const int lane = t&63, wv = t>>6;
  const int mq = wv&1, nq = wv>>1;
  const int col = lane&15, qr = lane>>4;
  const size_t loff = (size_t)lane*8;
  const int ptA0 = (m0>>4) + mq*4;
  const int ntB0 = (n0>>4) + nq*4;
  f32x4 acc[4][4];
  #pragma unroll
  for (int i=0;i<4;i++)
    #pragma unroll
    for (int j=0;j<4;j++) acc[i][j] = (f32x4){0.f,0.f,0.f,0.f};

  for (int kk=0; kk<kkc; kk++){
    bf16x8 a[4][2];
    #pragma unroll
    for (int mi=0;mi<4;mi++){
      const size_t ab = (((size_t)(ptA0+mi)*kkc + kk)*2)*512 + loff;
      a[mi][0] = *(const bf16x8*)&af[ab];
      a[mi][1] = *(const bf16x8*)&af[ab+512];
    }
    #pragma unroll
    for (int ni=0;ni<4;ni++){
      const size_t bb = (((size_t)(ntB0+ni)*kkc + kk)*2)*512 + loff;
      const bf16x8 b1 = *(const bf16x8*)&bf[bb];
      const bf16x8 b2 = *(const bf16x8*)&bf[bb+512];
      #pragma unroll
      for (int mi=0;mi<4;mi++){
        f32x4 c = acc[mi][ni];
        c = __builtin_amdgcn_mfma_f32_16x16x32_bf16(a[mi][0], b1, c, 0,0,0);
        c = __builtin_amdgcn_mfma_f32_16x16x32_bf16(a[mi][0], b2, c, 0,0,0);
        c = __builtin_amdgcn_mfma_f32_16x16x32_bf16(a[mi][1], b1, c, 0,0,0);
        acc[mi][ni] = c;
      }
    }
  }
  float bb4[4];
  #pragma unroll
  for (int ni=0;ni<4;ni++) bb4[ni] = bias[n0 + nq*64 + ni*16 + col];
  // epilogue: leaky-relu then 2-way split store into h1f frag layout (kkc2=24).
  // pad rows (>=7200) contain finite junk fed from tiny-denormal pad tiles;
  // consumed only by discarded rows downstream.
  #pragma unroll
  for (int mi=0;mi<4;mi++){
    const int rt2 = (m0>>4) + mq*4 + mi;
    #pragma unroll
    for (int r=0;r<4;r++){
      #pragma unroll
      for (int ni=0;ni<4;ni++){
        float v = f4c(*(const float4*)&acc[mi][ni], r) + bb4[ni];
        v = v > 0.f ? v : 0.2f*v;
        u16 s1 = bfrn(v);
        u16 s2 = bfrn(v - bf2f(s1));
        const int kk2 = (n0>>5) + nq*2 + (ni>>1);
        const int qn = (ni&1)*2 + (col>>3);
        const size_t ob = ((size_t)(rt2*24 + kk2)*2)*512 + (qn*16 + qr*4 + r)*8 + (col&7);
        h1f[ob] = s1; h1f[ob+512] = s2;
      }
    }
  }
}

// ---------------- MLP layer 2: split-frag in, fp32 out + tanh ----------------
__global__ __launch_bounds__(256,2) void mlp2_k(
    const u16* __restrict__ af, const u16* __restrict__ bf,
    const float* __restrict__ bias, float* __restrict__ C){
  const int kkc = HID >> 5;      // 24
  const int t = threadIdx.x;
  const int n0 = blockIdx.x*128, m0 = blockIdx.y*128;
  const int lane = t&63, wv = t>>6;
  const int mq = wv&1, nq = wv>>1;
  const int col = lane&15, qr = lane>>4;
  const size_t loff = (size_t)lane*8;
  const int ptA0 = (m0>>4) + mq*4;
  const int ntB0 = (n0>>4) + nq*4;
  f32x4 acc[4][4];
  #pragma unroll
  for (int i=0;i<4;i++)
    #pragma unroll
    for (int j=0;j<4;j++) acc[i][j] = (f32x4){0.f,0.f,0.f,0.f};

  for (int kk=0; kk<kkc; kk++){
    bf16x8 a[4][2];
    #pragma unroll
    for (int mi=0;mi<4;mi++){
      const size_t ab = (((size_t)(ptA0+mi)*kkc + kk)*2)*512 + loff;
      a[mi][0] = *(const bf16x8*)&af[ab];
      a[mi][1] = *(const bf16x8*)&af[ab+512];
    }
    #pragma unroll
    for (int ni=0;ni<4;ni++){
      const size_t bb = (((size_t)(ntB0+ni)*kkc + kk)*2)*512 + loff;
      const bf16x8 b1 = *(const bf16x8*)&bf[bb];
      const bf16x8 b2 = *(const bf16x8*)&bf[bb+512];
      #pragma unroll
      for (int mi=0;mi<4;mi++){
        f32x4 c = acc[mi][ni];
        c = __builtin_amdgcn_mfma_f32_16x16x32_bf16(a[mi][0], b1, c, 0,0,0);
        c = __builtin_amdgcn_mfma_f32_16x16x32_bf16(a[mi][0], b2, c, 0,0,0);
        c = __builtin_amdgcn_mfma_f32_16x16x32_bf16(a[mi][1], b1, c, 0,0,0);
        acc[mi][ni] = c;
      }
    }
  }
  float bb4[4];
  #pragma unroll
  for (int ni=0;ni<4;ni++) bb4[ni] = bias[n0 + nq*64 + ni*16 + col];
  #pragma unroll
  for (int mi=0;mi<4;mi++){
    #pragma unroll
    for (int r=0;r<4;r++){
      const int row = m0 + mq*64 + mi*16 + qr*4 + r;
      if (row < NPATCH){
        #pragma unroll
        for (int ni=0;ni<4;ni++){
          float v = f4c(*(const float4*)&acc[mi][ni], r) + bb4[ni];
          C[(size_t)row*CHN + n0 + nq*64 + ni*16 + col] = tanhf(v);
        }
      }
    }
  }
}

extern "C" void kernel_launch(void* const* d_in, const int* in_sizes, int n_in,
                              void* d_out, int out_size, void* d_ws, size_t ws_size,
                              hipStream_t stream){
  const float* x  = (const float*)d_in[0];
  const float* cw = (const float*)d_in[1];
  const float* W1 = (const float*)d_in[2];
  const float* b1 = (const float*)d_in[3];
  const float* W2 = (const float*)d_in[4];
  const float* b2 = (const float*)d_in[5];
  float* out = (float*)d_out;
  float* ws = (float*)d_ws;
  float* invpix = ws;                                        // TOTPIX
  float* invw   = invpix + TOTPIX;                           // 512
  float* mcand  = invw + VCN;                                // TOTPIX*4
  float* sumsq  = mcand;   // alias: consumed by pixfin before gemm_z writes mcand
  int*   vcand  = (int*)(mcand + (size_t)TOTPIX*4);          // TOTPIX*4
  u16*   xf     = (u16*)(vcand + (size_t)TOTPIX*4);          // 113.2 MB
  u16*   wf     = xf + (size_t)(TOTPIX/16)*8*3*512;
  u16*   w1f    = wf + (size_t)32*8*3*512;
  u16*   w2f    = w1f + (size_t)48*10*2*512;
  u16*   inpf   = w2f + (size_t)16*24*2*512;                 // MTP*10*2*512 (9.3 MB)
  __half* zf    = (__half*)(inpf + (size_t)MTP*10*2*512);    // 75.5 MB
  u16*   h1f    = (u16*)zf;  // alias: zf dead after select_k; h1f written after
  // total ws use ~203 MB

  hipMemsetAsync(sumsq, 0, (size_t)TOTPIX*sizeof(float), stream);
  wsplit_k<3><<<dim3(VCN/16, CHN/32),64,0,stream>>>(cw, wf, CHN);
  wsplit_k<2><<<dim3(HID/16, INPD/32),64,0,stream>>>(W1, w1f, INPD);
  wsplit_k<2><<<dim3(CHN/16, HID/32),64,0,stream>>>(W2, w2f, HID);
  wnorm_k<<<2,256,0,stream>>>(cw, invw);
  xsplit_k<<<dim3(PIXN/64, CHN/64, NB),256,0,stream>>>(x, xf, sumsq);
  pixfin_k<<<TOTPIX/256,256,0,stream>>>(sumsq, invpix);
  gemm_z_k<<<dim3(VCN/128, TOTPIX/128),256,0,stream>>>(xf, wf, invpix, invw, mcand, vcand, zf);
  select_k<<<NPATCH,64,0,stream>>>(xf, cw, zf, mcand, vcand, inpf);
  mlp1_k<<<dim3(HID/128, (NPATCH+127)/128),256,0,stream>>>(inpf, w1f, b1, h1f);
  mlp2_k<<<dim3(CHN/128, (NPATCH+127)/128),256,0,stream>>>(h1f, w2f, b2, out);
}